// Round 10
// baseline (4422.882 us; speedup 1.0000x reference)
//
#include <hip/hip_runtime.h>
#include <hip/hip_bf16.h>

#define THREADS 256
#define NB 256        // row buckets for uu CSR build (512 rows each)
#define CHUNK 2048    // edges per partition block
#define EPT 8         // CHUNK / THREADS

typedef unsigned long long u64;

// ---------------------------------------------------------------------------
// uu build: bucket hist -> scan -> LDS-staged partition (row buckets) ->
// per-bucket counting sort by col-group (col>>9). Payload (u64):
// [63:32]=val bits, [28:20]=rloc (row & 511), [19:0]=col
// ---------------------------------------------------------------------------

__global__ __launch_bounds__(THREADS) void bucket_hist(
    const int* __restrict__ rows, int nnz, int bshift, int* __restrict__ bcnt)
{
    __shared__ int h[NB];
    h[threadIdx.x] = 0;
    __syncthreads();
    long long stride = (long long)gridDim.x * THREADS;
    for (long long e = (long long)blockIdx.x * THREADS + threadIdx.x; e < nnz; e += stride)
        atomicAdd(&h[rows[e] >> bshift], 1);
    __syncthreads();
    int v = h[threadIdx.x];
    if (v) atomicAdd(&bcnt[threadIdx.x], v);
}

__global__ void scan_buckets(const int* __restrict__ bcnt, int* __restrict__ bbase,
                             int* __restrict__ gcur)
{
    if (threadIdx.x == 0 && blockIdx.x == 0) {
        int run = 0;
        for (int i = 0; i < NB; i++) { bbase[i] = run; gcur[i] = run; run += bcnt[i]; }
        bbase[NB] = run;
    }
}

__global__ __launch_bounds__(THREADS) void partition_uu(
    const int* __restrict__ rows, const int* __restrict__ cols,
    const float* __restrict__ vals, int nnz, int bshift,
    u64* __restrict__ mid, int* __restrict__ gcur)
{
    __shared__ int hist[NB], lbase[NB], lcur[NB], gbase[NB];
    __shared__ u64 stage[CHUNK];
    __shared__ int dst[CHUNK];
    int t = threadIdx.x;
    long long cb = (long long)blockIdx.x * CHUNK;
    hist[t] = 0; lcur[t] = 0;
    __syncthreads();

    int rl[EPT], cl[EPT], vb[EPT];
    #pragma unroll
    for (int j = 0; j < EPT; j++) {
        long long e = cb + j * THREADS + t;
        if (e < nnz) {
            rl[j] = rows[e]; cl[j] = cols[e]; vb[j] = __float_as_int(vals[e]);
            atomicAdd(&hist[rl[j] >> bshift], 1);
        } else rl[j] = -1;
    }
    __syncthreads();

    int v = hist[t];
    lbase[t] = v;
    __syncthreads();
    for (int off = 1; off < NB; off <<= 1) {
        int add = (t >= off) ? lbase[t - off] : 0;
        __syncthreads();
        lbase[t] += add;
        __syncthreads();
    }
    int excl = lbase[t] - v;
    int gb = 0;
    if (v) gb = atomicAdd(&gcur[t], v);
    gbase[t] = gb;
    lbase[t] = excl;
    __syncthreads();

    #pragma unroll
    for (int j = 0; j < EPT; j++) {
        if (rl[j] >= 0) {
            int b = rl[j] >> bshift;
            int rank = atomicAdd(&lcur[b], 1);
            int pos = lbase[b] + rank;
            stage[pos] = ((u64)(unsigned)vb[j] << 32)
                       | ((unsigned)(rl[j] & ((1 << bshift) - 1)) << 20)
                       | (unsigned)cl[j];
            dst[pos] = gbase[b] + rank;
        }
    }
    __syncthreads();
    int total = lbase[NB - 1] + hist[NB - 1];
    for (int i = t; i < total; i += THREADS)
        mid[dst[i]] = stage[i];
}

// Counting sort of each bucket's edges by col-group (col>>9, 256 groups).
// Imposes col-locality on the SpMM gather stream.
__global__ __launch_bounds__(THREADS) void fine_col(
    const u64* __restrict__ mid, const int* __restrict__ bbase,
    u64* __restrict__ se)
{
    __shared__ int gcnt[256], gb[256];
    int b = blockIdx.x, t = threadIdx.x;
    int s = bbase[b], e = bbase[b + 1];
    gcnt[t] = 0;
    __syncthreads();
    for (int i = s + t; i < e; i += THREADS)
        atomicAdd(&gcnt[(int)((mid[i] >> 9) & 255)], 1);   // col>>9 (col<2^17)
    __syncthreads();
    int v = gcnt[t];
    gb[t] = v;
    __syncthreads();
    for (int off = 1; off < 256; off <<= 1) {
        int add = (t >= off) ? gb[t - off] : 0;
        __syncthreads();
        gb[t] += add;
        __syncthreads();
    }
    gcnt[t] = gb[t] - v;      // exclusive base -> cursor
    __syncthreads();
    for (int i = s + t; i < e; i += THREADS) {
        u64 w = mid[i];
        int k = (int)((w >> 9) & 255);
        int pos = s + atomicAdd(&gcnt[k], 1);
        se[pos] = w;
    }
}

// ---------------------------------------------------------------------------
// Tiled uu-SpMM: block = (bucket, row-half). 256-row y-tile in LDS (64 KB,
// k-plane layout). Streams col-sorted bucket edges; 16-lane float4 gathers
// predicated on row-half; LDS atomic accumulate; coalesced epilogue with
// mode folding. mode: 1 = acc store, 2 = acc add, 3 = acc = 0.25*(ue+acc+a)
// ---------------------------------------------------------------------------
__global__ __launch_bounds__(THREADS) void spmm_tile(
    const u64* __restrict__ se, const int* __restrict__ bbase,
    const float* __restrict__ x, float* __restrict__ y,
    float* __restrict__ acc, const float* __restrict__ ue, int mode)
{
    __shared__ float yt[16384];              // 4 k-planes of [256 rows][16 quads]
    int bk = blockIdx.x >> 1;
    int h  = blockIdx.x & 1;
    int t = threadIdx.x;

    float4* ytv = (float4*)yt;
    #pragma unroll
    for (int i = 0; i < 16; i++) ytv[t + 256 * i] = make_float4(0.f, 0.f, 0.f, 0.f);
    __syncthreads();

    int s = bbase[bk], e = bbase[bk + 1];
    int lane = t & 63;
    int g = lane >> 4, fl = lane & 15;
    int wv = t >> 6;
    const float4* __restrict__ x4 = (const float4*)x;

    for (int base = s + wv * 64; base < e; base += 256) {
        int avail = e - base;
        u64 p = 0;
        if (lane < avail)
            p = __builtin_nontemporal_load(se + base + lane);
        int evc = (int)(p & 0xFFFFF);
        int evr = (int)((p >> 20) & 0x1FF);
        int evv = (int)(p >> 32);
        int n = avail < 64 ? avail : 64;
        #pragma unroll 4
        for (int j = 0; j < 16; j++) {
            int idx = j * 4 + g;
            int c = __shfl(evc, idx);
            int r = __shfl(evr, idx);
            float v = __int_as_float(__shfl(evv, idx));
            if (idx < n && (r >> 8) == h) {
                float4 xv = x4[((long long)c << 4) + fl];
                int rb = (r & 255) * 16 + fl;
                atomicAdd(&yt[rb], v * xv.x);
                atomicAdd(&yt[4096 + rb], v * xv.y);
                atomicAdd(&yt[8192 + rb], v * xv.z);
                atomicAdd(&yt[12288 + rb], v * xv.w);
            }
        }
    }
    __syncthreads();

    // epilogue: 16 rows per iteration, thread t -> row r0+(t>>4), quad t&15
    for (int r0 = 0; r0 < 256; r0 += 16) {
        int r = r0 + (t >> 4);
        int q = t & 15;
        int li = r * 16 + q;
        float4 o;
        o.x = yt[li];
        o.y = yt[4096 + li];
        o.z = yt[8192 + li];
        o.w = yt[12288 + li];
        long long row = ((long long)bk << 9) + ((long long)h << 8) + r;
        long long oi = row * 16 + q;
        if (y) ((float4*)y)[oi] = o;
        if (mode == 1) {
            ((float4*)acc)[oi] = o;
        } else if (mode == 2) {
            float4 a = ((float4*)acc)[oi];
            a.x += o.x; a.y += o.y; a.z += o.z; a.w += o.w;
            ((float4*)acc)[oi] = a;
        } else if (mode == 3) {
            float4 a = ((float4*)acc)[oi];
            float4 u = ((const float4*)ue)[oi];
            a.x = 0.25f * (u.x + a.x + o.x);
            a.y = 0.25f * (u.y + a.y + o.y);
            a.z = 0.25f * (u.z + a.z + o.z);
            a.w = 0.25f * (u.w + a.w + o.w);
            ((float4*)acc)[oi] = a;
        }
    }
}

// ---------------------------------------------------------------------------
// g-graph build (filtered): hist -> scan -> scatter
// ---------------------------------------------------------------------------

__global__ __launch_bounds__(THREADS) void hist_g(
    const int* __restrict__ rows, const int* __restrict__ cols,
    int nnz, int* __restrict__ cnt, int nU)
{
    int stride = gridDim.x * THREADS;
    for (int e = blockIdx.x * THREADS + threadIdx.x; e < nnz; e += stride) {
        int r = rows[e];
        if (r >= nU && cols[e] < nU) atomicAdd(&cnt[r - nU], 1);
    }
}

__global__ __launch_bounds__(THREADS) void scan_block_sums(
    const int* __restrict__ cnt, int* __restrict__ partial)
{
    __shared__ int lds[THREADS];
    int i = blockIdx.x * 512 + threadIdx.x * 2;
    lds[threadIdx.x] = cnt[i] + cnt[i + 1];
    __syncthreads();
    for (int off = 128; off > 0; off >>= 1) {
        if (threadIdx.x < off) lds[threadIdx.x] += lds[threadIdx.x + off];
        __syncthreads();
    }
    if (threadIdx.x == 0) partial[blockIdx.x] = lds[0];
}

__global__ void scan_partials(int* partial, int nb, int* rp, int n)
{
    if (threadIdx.x == 0 && blockIdx.x == 0) {
        int run = 0;
        for (int i = 0; i < nb; i++) { int v = partial[i]; partial[i] = run; run += v; }
        rp[n] = run;
    }
}

__global__ __launch_bounds__(THREADS) void scan_write(
    const int* __restrict__ cnt, const int* __restrict__ partial, int* __restrict__ rp)
{
    __shared__ int lds[THREADS];
    int t = threadIdx.x;
    int i = blockIdx.x * 512 + t * 2;
    int a0 = cnt[i], a1 = cnt[i + 1];
    int s = a0 + a1;
    lds[t] = s;
    __syncthreads();
    for (int off = 1; off < THREADS; off <<= 1) {
        int v = (t >= off) ? lds[t - off] : 0;
        __syncthreads();
        lds[t] += v;
        __syncthreads();
    }
    int excl = lds[t] - s;
    int base = partial[blockIdx.x];
    rp[i] = base + excl;
    rp[i + 1] = base + excl + a0;
}

__global__ __launch_bounds__(THREADS) void scatter_g(
    const int* __restrict__ rows, const int* __restrict__ cols,
    const float* __restrict__ vals, int nnz, int* __restrict__ cur,
    int2* __restrict__ se, int nU)
{
    int stride = gridDim.x * THREADS;
    for (int e = blockIdx.x * THREADS + threadIdx.x; e < nnz; e += stride) {
        int r = rows[e];
        if (r >= nU) {
            int c = cols[e];
            if (c < nU) {
                int p = atomicAdd(&cur[r - nU], 1);
                se[p] = make_int2(c, __float_as_int(vals[e]));
            }
        }
    }
}

// ---------------------------------------------------------------------------
// Gather SpMM (kept for the g layer): wave per row, float4 slot-gather.
// ---------------------------------------------------------------------------
__global__ __launch_bounds__(THREADS) void spmm_csr3(
    const int* __restrict__ rp, const long long* __restrict__ se,
    const float* __restrict__ x, float* __restrict__ y, int nrows)
{
    int w = (blockIdx.x * THREADS + threadIdx.x) >> 6;
    int lane = threadIdx.x & 63;
    if (w >= nrows) return;
    int s = rp[w], e = rp[w + 1];
    int g  = lane >> 4;
    int fl = lane & 15;

    const float4* __restrict__ x4 = (const float4*)x;

    float4 A0 = {0,0,0,0}, A1 = {0,0,0,0}, A2 = {0,0,0,0}, A3 = {0,0,0,0};
    float4 A4 = {0,0,0,0}, A5 = {0,0,0,0}, A6 = {0,0,0,0}, A7 = {0,0,0,0};

    for (int base = s; base < e; base += 64) {
        int avail = e - base;
        long long packed = 0;
        if (lane < avail)
            packed = __builtin_nontemporal_load(se + base + lane);
        int evc = (int)(packed & 0xffffffffLL);
        int evv = (int)(packed >> 32);
        int n = avail < 64 ? avail : 64;
        int nSlot = (n + 3) >> 2;
        int nIter = (nSlot + 7) & ~7;
        for (int j0 = 0; j0 < nIter; j0 += 8) {
            int idx0 = (j0 + 0) * 4 + g, idx1 = (j0 + 1) * 4 + g;
            int idx2 = (j0 + 2) * 4 + g, idx3 = (j0 + 3) * 4 + g;
            int idx4 = (j0 + 4) * 4 + g, idx5 = (j0 + 5) * 4 + g;
            int idx6 = (j0 + 6) * 4 + g, idx7 = (j0 + 7) * 4 + g;
            int   c0 = __shfl(evc, idx0); float v0 = __int_as_float(__shfl(evv, idx0));
            int   c1 = __shfl(evc, idx1); float v1 = __int_as_float(__shfl(evv, idx1));
            int   c2 = __shfl(evc, idx2); float v2 = __int_as_float(__shfl(evv, idx2));
            int   c3 = __shfl(evc, idx3); float v3 = __int_as_float(__shfl(evv, idx3));
            int   c4 = __shfl(evc, idx4); float v4 = __int_as_float(__shfl(evv, idx4));
            int   c5 = __shfl(evc, idx5); float v5 = __int_as_float(__shfl(evv, idx5));
            int   c6 = __shfl(evc, idx6); float v6 = __int_as_float(__shfl(evv, idx6));
            int   c7 = __shfl(evc, idx7); float v7 = __int_as_float(__shfl(evv, idx7));
            float4 g0 = x4[((long long)c0 << 4) + fl];
            float4 g1 = x4[((long long)c1 << 4) + fl];
            float4 g2 = x4[((long long)c2 << 4) + fl];
            float4 g3 = x4[((long long)c3 << 4) + fl];
            float4 g4 = x4[((long long)c4 << 4) + fl];
            float4 g5 = x4[((long long)c5 << 4) + fl];
            float4 g6 = x4[((long long)c6 << 4) + fl];
            float4 g7 = x4[((long long)c7 << 4) + fl];
            A0.x += v0 * g0.x; A0.y += v0 * g0.y; A0.z += v0 * g0.z; A0.w += v0 * g0.w;
            A1.x += v1 * g1.x; A1.y += v1 * g1.y; A1.z += v1 * g1.z; A1.w += v1 * g1.w;
            A2.x += v2 * g2.x; A2.y += v2 * g2.y; A2.z += v2 * g2.z; A2.w += v2 * g2.w;
            A3.x += v3 * g3.x; A3.y += v3 * g3.y; A3.z += v3 * g3.z; A3.w += v3 * g3.w;
            A4.x += v4 * g4.x; A4.y += v4 * g4.y; A4.z += v4 * g4.z; A4.w += v4 * g4.w;
            A5.x += v5 * g5.x; A5.y += v5 * g5.y; A5.z += v5 * g5.z; A5.w += v5 * g5.w;
            A6.x += v6 * g6.x; A6.y += v6 * g6.y; A6.z += v6 * g6.z; A6.w += v6 * g6.w;
            A7.x += v7 * g7.x; A7.y += v7 * g7.y; A7.z += v7 * g7.z; A7.w += v7 * g7.w;
        }
    }

    float4 r;
    r.x = ((A0.x + A1.x) + (A2.x + A3.x)) + ((A4.x + A5.x) + (A6.x + A7.x));
    r.y = ((A0.y + A1.y) + (A2.y + A3.y)) + ((A4.y + A5.y) + (A6.y + A7.y));
    r.z = ((A0.z + A1.z) + (A2.z + A3.z)) + ((A4.z + A5.z) + (A6.z + A7.z));
    r.w = ((A0.w + A1.w) + (A2.w + A3.w)) + ((A4.w + A5.w) + (A6.w + A7.w));
    r.x += __shfl_xor(r.x, 16); r.x += __shfl_xor(r.x, 32);
    r.y += __shfl_xor(r.y, 16); r.y += __shfl_xor(r.y, 32);
    r.z += __shfl_xor(r.z, 16); r.z += __shfl_xor(r.z, 32);
    r.w += __shfl_xor(r.w, 16); r.w += __shfl_xor(r.w, 32);

    if (g == 0) {
        long long oi = ((long long)w << 4) + fl;
        ((float4*)y)[oi] = r;
    }
}

__global__ __launch_bounds__(THREADS) void final_dot_kernel(
    const float* __restrict__ au, const float* __restrict__ it,
    const int* __restrict__ users, const int* __restrict__ items,
    float* __restrict__ out, int B)
{
    int gid = blockIdx.x * THREADS + threadIdx.x;
    int b = gid >> 4;
    if (b >= B) return;
    int part = gid & 15;
    float4 uv = reinterpret_cast<const float4*>(au)[(long long)users[b] * 16 + part];
    float4 iv = reinterpret_cast<const float4*>(it)[(long long)items[b] * 16 + part];
    float s = uv.x * iv.x + uv.y * iv.y + uv.z * iv.z + uv.w * iv.w;
    s += __shfl_xor(s, 1);
    s += __shfl_xor(s, 2);
    s += __shfl_xor(s, 4);
    s += __shfl_xor(s, 8);
    if (part == 0) out[b] = s;
}

// ---------------------------------------------------------------------------
// Fallback (atomic path) in case ws/shape assumptions fail
// ---------------------------------------------------------------------------
__global__ __launch_bounds__(THREADS) void spmm_atomic_kernel(
    const int* __restrict__ rows, const int* __restrict__ cols,
    const float* __restrict__ vals, const float* __restrict__ x,
    float* __restrict__ y, int nnz)
{
    long long gid = (long long)blockIdx.x * THREADS + threadIdx.x;
    int e = (int)(gid >> 4);
    if (e >= nnz) return;
    int part = (int)(gid & 15);
    int r = rows[e];
    int c = cols[e];
    float v = vals[e];
    float4 xv = reinterpret_cast<const float4*>(x)[(long long)c * 16 + part];
    float* yp = y + (long long)r * 64 + part * 4;
    atomicAdd(yp + 0, v * xv.x);
    atomicAdd(yp + 1, v * xv.y);
    atomicAdd(yp + 2, v * xv.z);
    atomicAdd(yp + 3, v * xv.w);
}

__global__ __launch_bounds__(THREADS) void spmm_g_items_kernel(
    const int* __restrict__ rows, const int* __restrict__ cols,
    const float* __restrict__ vals, const float* __restrict__ x,
    float* __restrict__ y_items, int nnz, int nU)
{
    long long gid = (long long)blockIdx.x * THREADS + threadIdx.x;
    int e = (int)(gid >> 4);
    if (e >= nnz) return;
    int r = rows[e];
    if (r < nU) return;
    int c = cols[e];
    if (c >= nU) return;
    int part = (int)(gid & 15);
    float v = vals[e];
    float4 xv = reinterpret_cast<const float4*>(x)[(long long)c * 16 + part];
    float* yp = y_items + (long long)(r - nU) * 64 + part * 4;
    atomicAdd(yp + 0, v * xv.x);
    atomicAdd(yp + 1, v * xv.y);
    atomicAdd(yp + 2, v * xv.z);
    atomicAdd(yp + 3, v * xv.w);
}

__global__ __launch_bounds__(THREADS) void combine_kernel(
    const float4* __restrict__ e0, float4* __restrict__ e1,
    const float4* __restrict__ e2, const float4* __restrict__ e3, int n4)
{
    int i = blockIdx.x * THREADS + threadIdx.x;
    if (i >= n4) return;
    float4 a = e0[i], b = e1[i], c = e2[i], d = e3[i];
    e1[i] = make_float4(0.25f * (a.x + b.x + c.x + d.x), 0.25f * (a.y + b.y + c.y + d.y),
                        0.25f * (a.z + b.z + c.z + d.z), 0.25f * (a.w + b.w + c.w + d.w));
}

// ---------------------------------------------------------------------------

extern "C" void kernel_launch(void* const* d_in, const int* in_sizes, int n_in,
                              void* d_out, int out_size, void* d_ws, size_t ws_size,
                              hipStream_t stream) {
    const float* user_emb = (const float*)d_in[0];
    const int*   uu_rows  = (const int*)d_in[1];
    const int*   uu_cols  = (const int*)d_in[2];
    const float* uu_vals  = (const float*)d_in[3];
    const int*   g_rows   = (const int*)d_in[4];
    const int*   g_cols   = (const int*)d_in[5];
    const float* g_vals   = (const float*)d_in[6];
    const int*   users    = (const int*)d_in[7];
    const int*   items    = (const int*)d_in[8];

    const int U    = in_sizes[0] / 64;     // 131072
    const int E_UU = in_sizes[1];          // 4000000
    const int E_G  = in_sizes[4];          // 4000000
    const int B    = in_sizes[7];          // 8192
    const int M    = 32768;                // num_items (fixed per reference)

    const size_t EMB = (size_t)U * 64 * sizeof(float);   // 32 MB
    const size_t MB  = 1024 * 1024;

    char* ws = (char*)d_ws;

    float* ACC = (float*)(ws);
    float* P0  = (float*)(ws + EMB);
    float* P1  = (float*)(ws + 2 * EMB);
    u64*   mid = (u64*)(ws);                               // aliases ACC during build
    int*  cnt_g = (int*)(ws + EMB);
    int*  rp_g  = (int*)(ws + EMB + 512 * 1024);
    int*  cur_g = (int*)(ws + EMB + 1 * MB);
    int2* se_g  = (int2*)(ws + EMB + MB + 512 * 1024);
    float* IT   = (float*)(ws + EMB + 34 * MB);
    char* base3 = ws + 3 * EMB;
    int*  bcnt    = (int*)(base3);
    int*  gcur    = (int*)(base3 + 4096);
    int*  bbase   = (int*)(base3 + 8192);
    int*  partial = (int*)(base3 + 1 * MB);
    u64*  se_u  = (u64*)(base3 + 2 * MB + 16 * 1024);
    const size_t needCSR = 3 * EMB + 2 * MB + 16 * 1024 + (size_t)E_UU * 8 + 1024;

    int n4 = U * 16;

    bool newPath = (ws_size >= needCSR) && (U == 131072) &&
                   ((size_t)E_UU * 8 <= EMB) && (E_UU > 0);

    if (newPath) {
        const int bshift = 9;
        // ---- build uu: row-bucket partition + col-group sort ----
        hipMemsetAsync(bcnt, 0, NB * 4, stream);
        bucket_hist<<<1024, THREADS, 0, stream>>>(uu_rows, E_UU, bshift, bcnt);
        scan_buckets<<<1, 64, 0, stream>>>(bcnt, bbase, gcur);
        int nChunks = (E_UU + CHUNK - 1) / CHUNK;
        partition_uu<<<nChunks, THREADS, 0, stream>>>(uu_rows, uu_cols, uu_vals,
                                                      E_UU, bshift, mid, gcur);
        fine_col<<<NB, THREADS, 0, stream>>>(mid, bbase, se_u);

        // ---- 3 tiled layers; ACC folding in epilogue ----
        spmm_tile<<<NB * 2, THREADS, 0, stream>>>(se_u, bbase, user_emb, P0, ACC,
                                                  (const float*)nullptr, 1);
        spmm_tile<<<NB * 2, THREADS, 0, stream>>>(se_u, bbase, P0, P1, ACC,
                                                  (const float*)nullptr, 2);
        spmm_tile<<<NB * 2, THREADS, 0, stream>>>(se_u, bbase, P1, (float*)nullptr, ACC,
                                                  user_emb, 3);

        // ---- build g (item-row) CSR, filtered ----
        hipMemsetAsync(cnt_g, 0, (size_t)M * 4, stream);
        hist_g<<<4096, THREADS, 0, stream>>>(g_rows, g_cols, E_G, cnt_g, U);
        scan_block_sums<<<M / 512, THREADS, 0, stream>>>(cnt_g, partial);
        scan_partials<<<1, 64, 0, stream>>>(partial, M / 512, rp_g, M);
        scan_write<<<M / 512, THREADS, 0, stream>>>(cnt_g, partial, rp_g);
        hipMemcpyAsync(cur_g, rp_g, (size_t)M * 4, hipMemcpyDeviceToDevice, stream);
        scatter_g<<<4096, THREADS, 0, stream>>>(g_rows, g_cols, g_vals, E_G, cur_g, se_g, U);

        // ---- item propagation + gamma ----
        spmm_csr3<<<M / 4, THREADS, 0, stream>>>(rp_g, (const long long*)se_g, ACC, IT, M);
        final_dot_kernel<<<(B * 16 + THREADS - 1) / THREADS, THREADS, 0, stream>>>(
            ACC, IT, users, items, (float*)d_out, B);
    } else {
        // ---- fallback: atomic path ----
        float* E1 = (float*)ws;
        float* E2 = (float*)(ws + EMB);
        float* E3 = (float*)(ws + 2 * EMB);
        float* IT2 = (float*)(ws + 3 * EMB);
        const size_t itBytes = (size_t)M * 64 * sizeof(float);
        int spmmGrid = (int)(((long long)E_UU * 16 + THREADS - 1) / THREADS);
        int gGrid    = (int)(((long long)E_G * 16 + THREADS - 1) / THREADS);

        hipMemsetAsync(E1, 0, EMB, stream);
        spmm_atomic_kernel<<<spmmGrid, THREADS, 0, stream>>>(uu_rows, uu_cols, uu_vals, user_emb, E1, E_UU);
        hipMemsetAsync(E2, 0, EMB, stream);
        spmm_atomic_kernel<<<spmmGrid, THREADS, 0, stream>>>(uu_rows, uu_cols, uu_vals, E1, E2, E_UU);
        hipMemsetAsync(E3, 0, EMB, stream);
        spmm_atomic_kernel<<<spmmGrid, THREADS, 0, stream>>>(uu_rows, uu_cols, uu_vals, E2, E3, E_UU);
        combine_kernel<<<(n4 + THREADS - 1) / THREADS, THREADS, 0, stream>>>(
            (const float4*)user_emb, (float4*)E1, (const float4*)E2, (const float4*)E3, n4);
        hipMemsetAsync(IT2, 0, itBytes, stream);
        spmm_g_items_kernel<<<gGrid, THREADS, 0, stream>>>(g_rows, g_cols, g_vals, E1, IT2, E_G, U);
        final_dot_kernel<<<(B * 16 + THREADS - 1) / THREADS, THREADS, 0, stream>>>(
            E1, IT2, users, items, (float*)d_out, B);
    }
}

// Round 11
// 4212.599 us; speedup vs baseline: 1.0499x; 1.0499x over previous
//
#include <hip/hip_runtime.h>
#include <hip/hip_bf16.h>

#define THREADS 256
#define NB 256        // row buckets for uu build (512 rows each)
#define CHUNK 2048    // edges per partition block
#define EPT 8         // CHUNK / THREADS

typedef unsigned long long u64;

// ---------------------------------------------------------------------------
// uu build: bucket hist -> scan -> LDS-staged partition (512-row buckets) ->
// per-bucket counting sort by (row-half, col-group). Payload (u64):
// [63:32]=val bits, [28:20]=rloc (row & 511), [19:0]=col
// ---------------------------------------------------------------------------

__global__ __launch_bounds__(THREADS) void bucket_hist(
    const int* __restrict__ rows, int nnz, int bshift, int* __restrict__ bcnt)
{
    __shared__ int h[NB];
    h[threadIdx.x] = 0;
    __syncthreads();
    long long stride = (long long)gridDim.x * THREADS;
    for (long long e = (long long)blockIdx.x * THREADS + threadIdx.x; e < nnz; e += stride)
        atomicAdd(&h[rows[e] >> bshift], 1);
    __syncthreads();
    int v = h[threadIdx.x];
    if (v) atomicAdd(&bcnt[threadIdx.x], v);
}

__global__ void scan_buckets(const int* __restrict__ bcnt, int* __restrict__ bbase,
                             int* __restrict__ gcur, int* __restrict__ hbase, int E_)
{
    if (threadIdx.x == 0 && blockIdx.x == 0) {
        int run = 0;
        for (int i = 0; i < NB; i++) { bbase[i] = run; gcur[i] = run; run += bcnt[i]; }
        bbase[NB] = run;
        hbase[2 * NB] = E_;
    }
}

__global__ __launch_bounds__(THREADS) void partition_uu(
    const int* __restrict__ rows, const int* __restrict__ cols,
    const float* __restrict__ vals, int nnz, int bshift,
    u64* __restrict__ mid, int* __restrict__ gcur)
{
    __shared__ int hist[NB], lbase[NB], lcur[NB], gbase[NB];
    __shared__ u64 stage[CHUNK];
    __shared__ int dst[CHUNK];
    int t = threadIdx.x;
    long long cb = (long long)blockIdx.x * CHUNK;
    hist[t] = 0; lcur[t] = 0;
    __syncthreads();

    int rl[EPT], cl[EPT], vb[EPT];
    #pragma unroll
    for (int j = 0; j < EPT; j++) {
        long long e = cb + j * THREADS + t;
        if (e < nnz) {
            rl[j] = rows[e]; cl[j] = cols[e]; vb[j] = __float_as_int(vals[e]);
            atomicAdd(&hist[rl[j] >> bshift], 1);
        } else rl[j] = -1;
    }
    __syncthreads();

    int v = hist[t];
    lbase[t] = v;
    __syncthreads();
    for (int off = 1; off < NB; off <<= 1) {
        int add = (t >= off) ? lbase[t - off] : 0;
        __syncthreads();
        lbase[t] += add;
        __syncthreads();
    }
    int excl = lbase[t] - v;
    int gb = 0;
    if (v) gb = atomicAdd(&gcur[t], v);
    gbase[t] = gb;
    lbase[t] = excl;
    __syncthreads();

    #pragma unroll
    for (int j = 0; j < EPT; j++) {
        if (rl[j] >= 0) {
            int b = rl[j] >> bshift;
            int rank = atomicAdd(&lcur[b], 1);
            int pos = lbase[b] + rank;
            stage[pos] = ((u64)(unsigned)vb[j] << 32)
                       | ((unsigned)(rl[j] & ((1 << bshift) - 1)) << 20)
                       | (unsigned)cl[j];
            dst[pos] = gbase[b] + rank;
        }
    }
    __syncthreads();
    int total = lbase[NB - 1] + hist[NB - 1];
    for (int i = t; i < total; i += THREADS)
        mid[dst[i]] = stage[i];
}

// Counting sort of each 512-row bucket by key = (row-half<<8)|colgroup.
// Writes per-half edge bases to hbase so compute blocks stream only their own
// edges (branch-free inner loop), with col-locality within each half.
__global__ __launch_bounds__(THREADS) void fine_colh(
    const u64* __restrict__ mid, const int* __restrict__ bbase,
    u64* __restrict__ se, int* __restrict__ hbase)
{
    __shared__ int kcnt[512];
    __shared__ int sc[THREADS];
    int b = blockIdx.x, t = threadIdx.x;
    int s = bbase[b], e = bbase[b + 1];
    kcnt[t] = 0; kcnt[t + 256] = 0;
    __syncthreads();
    for (int i = s + t; i < e; i += THREADS) {
        u64 w = mid[i];
        int key = (int)(((w >> 28) & 1) << 8) | (int)((w >> 9) & 255);
        atomicAdd(&kcnt[key], 1);
    }
    __syncthreads();
    int a0 = kcnt[2 * t], a1 = kcnt[2 * t + 1];
    int psum = a0 + a1;
    sc[t] = psum;
    __syncthreads();
    for (int off = 1; off < THREADS; off <<= 1) {
        int add = (t >= off) ? sc[t - off] : 0;
        __syncthreads();
        sc[t] += add;
        __syncthreads();
    }
    int pexcl = sc[t] - psum;
    if (t == 0)   hbase[2 * b] = s;
    if (t == 128) hbase[2 * b + 1] = s + pexcl;   // base of key 256 = half-1 start
    kcnt[2 * t] = pexcl;
    kcnt[2 * t + 1] = pexcl + a0;
    __syncthreads();
    for (int i = s + t; i < e; i += THREADS) {
        u64 w = mid[i];
        int key = (int)(((w >> 28) & 1) << 8) | (int)((w >> 9) & 255);
        int pos = s + atomicAdd(&kcnt[key], 1);
        se[pos] = w;
    }
}

// ---------------------------------------------------------------------------
// Tiled uu-SpMM v2: one block per (bucket, row-half) = 512 blocks, 64 KB LDS
// y-tile (4 k-planes of [256 rows][16 quads]). Branch-free inner loop:
// two 8-slot batches of {shfl-extract, float4 gather, 4 LDS atomicAdd}.
// Pad lanes carry {col=0,row=0,val=0.0} -> harmless +0.
// mode: 1 = acc store, 2 = acc add, 3 = acc = 0.25*(ue+acc+a)
// ---------------------------------------------------------------------------
__global__ __launch_bounds__(THREADS) void spmm_tile2(
    const u64* __restrict__ se, const int* __restrict__ hbase,
    const float* __restrict__ x, float* __restrict__ y,
    float* __restrict__ acc, const float* __restrict__ ue, int mode)
{
    __shared__ float yt[16384];
    int blk = blockIdx.x;
    int t = threadIdx.x;

    float4* ytv = (float4*)yt;
    #pragma unroll
    for (int i = 0; i < 16; i++) ytv[t + 256 * i] = make_float4(0.f, 0.f, 0.f, 0.f);
    __syncthreads();

    int s = hbase[blk], e = hbase[blk + 1];
    int lane = t & 63;
    int g = lane >> 4, fl = lane & 15;
    int wv = t >> 6;
    const float4* __restrict__ x4 = (const float4*)x;

    for (int base = s + wv * 64; base < e; base += 256) {
        int avail = e - base;
        u64 p = 0;
        if (lane < avail)
            p = __builtin_nontemporal_load(se + base + lane);
        int evc = (int)(p & 0xFFFFF);
        int evr = (int)((p >> 20) & 0xFF);     // row within 256-row half
        int evv = (int)(p >> 32);
        #pragma unroll
        for (int hb = 0; hb < 2; hb++) {
            int j0 = hb * 8;
            int i0 = (j0 + 0) * 4 + g, i1 = (j0 + 1) * 4 + g;
            int i2 = (j0 + 2) * 4 + g, i3 = (j0 + 3) * 4 + g;
            int i4 = (j0 + 4) * 4 + g, i5 = (j0 + 5) * 4 + g;
            int i6 = (j0 + 6) * 4 + g, i7 = (j0 + 7) * 4 + g;
            int c0 = __shfl(evc, i0); int r0 = __shfl(evr, i0); float v0 = __int_as_float(__shfl(evv, i0));
            int c1 = __shfl(evc, i1); int r1 = __shfl(evr, i1); float v1 = __int_as_float(__shfl(evv, i1));
            int c2 = __shfl(evc, i2); int r2 = __shfl(evr, i2); float v2 = __int_as_float(__shfl(evv, i2));
            int c3 = __shfl(evc, i3); int r3 = __shfl(evr, i3); float v3 = __int_as_float(__shfl(evv, i3));
            int c4 = __shfl(evc, i4); int r4 = __shfl(evr, i4); float v4 = __int_as_float(__shfl(evv, i4));
            int c5 = __shfl(evc, i5); int r5 = __shfl(evr, i5); float v5 = __int_as_float(__shfl(evv, i5));
            int c6 = __shfl(evc, i6); int r6 = __shfl(evr, i6); float v6 = __int_as_float(__shfl(evv, i6));
            int c7 = __shfl(evc, i7); int r7 = __shfl(evr, i7); float v7 = __int_as_float(__shfl(evv, i7));
            float4 g0 = x4[((long long)c0 << 4) + fl];
            float4 g1 = x4[((long long)c1 << 4) + fl];
            float4 g2 = x4[((long long)c2 << 4) + fl];
            float4 g3 = x4[((long long)c3 << 4) + fl];
            float4 g4 = x4[((long long)c4 << 4) + fl];
            float4 g5 = x4[((long long)c5 << 4) + fl];
            float4 g6 = x4[((long long)c6 << 4) + fl];
            float4 g7 = x4[((long long)c7 << 4) + fl];
            int b0 = r0 * 16 + fl, b1 = r1 * 16 + fl, b2 = r2 * 16 + fl, b3 = r3 * 16 + fl;
            int b4 = r4 * 16 + fl, b5 = r5 * 16 + fl, b6 = r6 * 16 + fl, b7 = r7 * 16 + fl;
            atomicAdd(&yt[b0], v0 * g0.x); atomicAdd(&yt[4096 + b0], v0 * g0.y);
            atomicAdd(&yt[8192 + b0], v0 * g0.z); atomicAdd(&yt[12288 + b0], v0 * g0.w);
            atomicAdd(&yt[b1], v1 * g1.x); atomicAdd(&yt[4096 + b1], v1 * g1.y);
            atomicAdd(&yt[8192 + b1], v1 * g1.z); atomicAdd(&yt[12288 + b1], v1 * g1.w);
            atomicAdd(&yt[b2], v2 * g2.x); atomicAdd(&yt[4096 + b2], v2 * g2.y);
            atomicAdd(&yt[8192 + b2], v2 * g2.z); atomicAdd(&yt[12288 + b2], v2 * g2.w);
            atomicAdd(&yt[b3], v3 * g3.x); atomicAdd(&yt[4096 + b3], v3 * g3.y);
            atomicAdd(&yt[8192 + b3], v3 * g3.z); atomicAdd(&yt[12288 + b3], v3 * g3.w);
            atomicAdd(&yt[b4], v4 * g4.x); atomicAdd(&yt[4096 + b4], v4 * g4.y);
            atomicAdd(&yt[8192 + b4], v4 * g4.z); atomicAdd(&yt[12288 + b4], v4 * g4.w);
            atomicAdd(&yt[b5], v5 * g5.x); atomicAdd(&yt[4096 + b5], v5 * g5.y);
            atomicAdd(&yt[8192 + b5], v5 * g5.z); atomicAdd(&yt[12288 + b5], v5 * g5.w);
            atomicAdd(&yt[b6], v6 * g6.x); atomicAdd(&yt[4096 + b6], v6 * g6.y);
            atomicAdd(&yt[8192 + b6], v6 * g6.z); atomicAdd(&yt[12288 + b6], v6 * g6.w);
            atomicAdd(&yt[b7], v7 * g7.x); atomicAdd(&yt[4096 + b7], v7 * g7.y);
            atomicAdd(&yt[8192 + b7], v7 * g7.z); atomicAdd(&yt[12288 + b7], v7 * g7.w);
        }
    }
    __syncthreads();

    // epilogue: thread t -> rows r0+(t>>4), quad t&15; global row = blk*256 + r
    for (int r0 = 0; r0 < 256; r0 += 16) {
        int r = r0 + (t >> 4);
        int q = t & 15;
        int li = r * 16 + q;
        float4 o;
        o.x = yt[li];
        o.y = yt[4096 + li];
        o.z = yt[8192 + li];
        o.w = yt[12288 + li];
        long long row = (long long)blk * 256 + r;
        long long oi = row * 16 + q;
        if (y) ((float4*)y)[oi] = o;
        if (mode == 1) {
            ((float4*)acc)[oi] = o;
        } else if (mode == 2) {
            float4 a = ((float4*)acc)[oi];
            a.x += o.x; a.y += o.y; a.z += o.z; a.w += o.w;
            ((float4*)acc)[oi] = a;
        } else if (mode == 3) {
            float4 a = ((float4*)acc)[oi];
            float4 u = ((const float4*)ue)[oi];
            a.x = 0.25f * (u.x + a.x + o.x);
            a.y = 0.25f * (u.y + a.y + o.y);
            a.z = 0.25f * (u.z + a.z + o.z);
            a.w = 0.25f * (u.w + a.w + o.w);
            ((float4*)acc)[oi] = a;
        }
    }
}

// ---------------------------------------------------------------------------
// g-graph build (filtered): hist -> scan -> scatter
// ---------------------------------------------------------------------------

__global__ __launch_bounds__(THREADS) void hist_g(
    const int* __restrict__ rows, const int* __restrict__ cols,
    int nnz, int* __restrict__ cnt, int nU)
{
    int stride = gridDim.x * THREADS;
    for (int e = blockIdx.x * THREADS + threadIdx.x; e < nnz; e += stride) {
        int r = rows[e];
        if (r >= nU && cols[e] < nU) atomicAdd(&cnt[r - nU], 1);
    }
}

__global__ __launch_bounds__(THREADS) void scan_block_sums(
    const int* __restrict__ cnt, int* __restrict__ partial)
{
    __shared__ int lds[THREADS];
    int i = blockIdx.x * 512 + threadIdx.x * 2;
    lds[threadIdx.x] = cnt[i] + cnt[i + 1];
    __syncthreads();
    for (int off = 128; off > 0; off >>= 1) {
        if (threadIdx.x < off) lds[threadIdx.x] += lds[threadIdx.x + off];
        __syncthreads();
    }
    if (threadIdx.x == 0) partial[blockIdx.x] = lds[0];
}

__global__ void scan_partials(int* partial, int nb, int* rp, int n)
{
    if (threadIdx.x == 0 && blockIdx.x == 0) {
        int run = 0;
        for (int i = 0; i < nb; i++) { int v = partial[i]; partial[i] = run; run += v; }
        rp[n] = run;
    }
}

__global__ __launch_bounds__(THREADS) void scan_write(
    const int* __restrict__ cnt, const int* __restrict__ partial, int* __restrict__ rp)
{
    __shared__ int lds[THREADS];
    int t = threadIdx.x;
    int i = blockIdx.x * 512 + t * 2;
    int a0 = cnt[i], a1 = cnt[i + 1];
    int s = a0 + a1;
    lds[t] = s;
    __syncthreads();
    for (int off = 1; off < THREADS; off <<= 1) {
        int v = (t >= off) ? lds[t - off] : 0;
        __syncthreads();
        lds[t] += v;
        __syncthreads();
    }
    int excl = lds[t] - s;
    int base = partial[blockIdx.x];
    rp[i] = base + excl;
    rp[i + 1] = base + excl + a0;
}

__global__ __launch_bounds__(THREADS) void scatter_g(
    const int* __restrict__ rows, const int* __restrict__ cols,
    const float* __restrict__ vals, int nnz, int* __restrict__ cur,
    int2* __restrict__ se, int nU)
{
    int stride = gridDim.x * THREADS;
    for (int e = blockIdx.x * THREADS + threadIdx.x; e < nnz; e += stride) {
        int r = rows[e];
        if (r >= nU) {
            int c = cols[e];
            if (c < nU) {
                int p = atomicAdd(&cur[r - nU], 1);
                se[p] = make_int2(c, __float_as_int(vals[e]));
            }
        }
    }
}

// ---------------------------------------------------------------------------
// Gather SpMM (g layer): wave per row, float4 slot-gather.
// ---------------------------------------------------------------------------
__global__ __launch_bounds__(THREADS) void spmm_csr3(
    const int* __restrict__ rp, const long long* __restrict__ se,
    const float* __restrict__ x, float* __restrict__ y, int nrows)
{
    int w = (blockIdx.x * THREADS + threadIdx.x) >> 6;
    int lane = threadIdx.x & 63;
    if (w >= nrows) return;
    int s = rp[w], e = rp[w + 1];
    int g  = lane >> 4;
    int fl = lane & 15;

    const float4* __restrict__ x4 = (const float4*)x;

    float4 A0 = {0,0,0,0}, A1 = {0,0,0,0}, A2 = {0,0,0,0}, A3 = {0,0,0,0};
    float4 A4 = {0,0,0,0}, A5 = {0,0,0,0}, A6 = {0,0,0,0}, A7 = {0,0,0,0};

    for (int base = s; base < e; base += 64) {
        int avail = e - base;
        long long packed = 0;
        if (lane < avail)
            packed = __builtin_nontemporal_load(se + base + lane);
        int evc = (int)(packed & 0xffffffffLL);
        int evv = (int)(packed >> 32);
        int n = avail < 64 ? avail : 64;
        int nSlot = (n + 3) >> 2;
        int nIter = (nSlot + 7) & ~7;
        for (int j0 = 0; j0 < nIter; j0 += 8) {
            int idx0 = (j0 + 0) * 4 + g, idx1 = (j0 + 1) * 4 + g;
            int idx2 = (j0 + 2) * 4 + g, idx3 = (j0 + 3) * 4 + g;
            int idx4 = (j0 + 4) * 4 + g, idx5 = (j0 + 5) * 4 + g;
            int idx6 = (j0 + 6) * 4 + g, idx7 = (j0 + 7) * 4 + g;
            int   c0 = __shfl(evc, idx0); float v0 = __int_as_float(__shfl(evv, idx0));
            int   c1 = __shfl(evc, idx1); float v1 = __int_as_float(__shfl(evv, idx1));
            int   c2 = __shfl(evc, idx2); float v2 = __int_as_float(__shfl(evv, idx2));
            int   c3 = __shfl(evc, idx3); float v3 = __int_as_float(__shfl(evv, idx3));
            int   c4 = __shfl(evc, idx4); float v4 = __int_as_float(__shfl(evv, idx4));
            int   c5 = __shfl(evc, idx5); float v5 = __int_as_float(__shfl(evv, idx5));
            int   c6 = __shfl(evc, idx6); float v6 = __int_as_float(__shfl(evv, idx6));
            int   c7 = __shfl(evc, idx7); float v7 = __int_as_float(__shfl(evv, idx7));
            float4 g0 = x4[((long long)c0 << 4) + fl];
            float4 g1 = x4[((long long)c1 << 4) + fl];
            float4 g2 = x4[((long long)c2 << 4) + fl];
            float4 g3 = x4[((long long)c3 << 4) + fl];
            float4 g4 = x4[((long long)c4 << 4) + fl];
            float4 g5 = x4[((long long)c5 << 4) + fl];
            float4 g6 = x4[((long long)c6 << 4) + fl];
            float4 g7 = x4[((long long)c7 << 4) + fl];
            A0.x += v0 * g0.x; A0.y += v0 * g0.y; A0.z += v0 * g0.z; A0.w += v0 * g0.w;
            A1.x += v1 * g1.x; A1.y += v1 * g1.y; A1.z += v1 * g1.z; A1.w += v1 * g1.w;
            A2.x += v2 * g2.x; A2.y += v2 * g2.y; A2.z += v2 * g2.z; A2.w += v2 * g2.w;
            A3.x += v3 * g3.x; A3.y += v3 * g3.y; A3.z += v3 * g3.z; A3.w += v3 * g3.w;
            A4.x += v4 * g4.x; A4.y += v4 * g4.y; A4.z += v4 * g4.z; A4.w += v4 * g4.w;
            A5.x += v5 * g5.x; A5.y += v5 * g5.y; A5.z += v5 * g5.z; A5.w += v5 * g5.w;
            A6.x += v6 * g6.x; A6.y += v6 * g6.y; A6.z += v6 * g6.z; A6.w += v6 * g6.w;
            A7.x += v7 * g7.x; A7.y += v7 * g7.y; A7.z += v7 * g7.z; A7.w += v7 * g7.w;
        }
    }

    float4 r;
    r.x = ((A0.x + A1.x) + (A2.x + A3.x)) + ((A4.x + A5.x) + (A6.x + A7.x));
    r.y = ((A0.y + A1.y) + (A2.y + A3.y)) + ((A4.y + A5.y) + (A6.y + A7.y));
    r.z = ((A0.z + A1.z) + (A2.z + A3.z)) + ((A4.z + A5.z) + (A6.z + A7.z));
    r.w = ((A0.w + A1.w) + (A2.w + A3.w)) + ((A4.w + A5.w) + (A6.w + A7.w));
    r.x += __shfl_xor(r.x, 16); r.x += __shfl_xor(r.x, 32);
    r.y += __shfl_xor(r.y, 16); r.y += __shfl_xor(r.y, 32);
    r.z += __shfl_xor(r.z, 16); r.z += __shfl_xor(r.z, 32);
    r.w += __shfl_xor(r.w, 16); r.w += __shfl_xor(r.w, 32);

    if (g == 0) {
        long long oi = ((long long)w << 4) + fl;
        ((float4*)y)[oi] = r;
    }
}

__global__ __launch_bounds__(THREADS) void final_dot_kernel(
    const float* __restrict__ au, const float* __restrict__ it,
    const int* __restrict__ users, const int* __restrict__ items,
    float* __restrict__ out, int B)
{
    int gid = blockIdx.x * THREADS + threadIdx.x;
    int b = gid >> 4;
    if (b >= B) return;
    int part = gid & 15;
    float4 uv = reinterpret_cast<const float4*>(au)[(long long)users[b] * 16 + part];
    float4 iv = reinterpret_cast<const float4*>(it)[(long long)items[b] * 16 + part];
    float s = uv.x * iv.x + uv.y * iv.y + uv.z * iv.z + uv.w * iv.w;
    s += __shfl_xor(s, 1);
    s += __shfl_xor(s, 2);
    s += __shfl_xor(s, 4);
    s += __shfl_xor(s, 8);
    if (part == 0) out[b] = s;
}

// ---------------------------------------------------------------------------
// Fallback (atomic path)
// ---------------------------------------------------------------------------
__global__ __launch_bounds__(THREADS) void spmm_atomic_kernel(
    const int* __restrict__ rows, const int* __restrict__ cols,
    const float* __restrict__ vals, const float* __restrict__ x,
    float* __restrict__ y, int nnz)
{
    long long gid = (long long)blockIdx.x * THREADS + threadIdx.x;
    int e = (int)(gid >> 4);
    if (e >= nnz) return;
    int part = (int)(gid & 15);
    int r = rows[e];
    int c = cols[e];
    float v = vals[e];
    float4 xv = reinterpret_cast<const float4*>(x)[(long long)c * 16 + part];
    float* yp = y + (long long)r * 64 + part * 4;
    atomicAdd(yp + 0, v * xv.x);
    atomicAdd(yp + 1, v * xv.y);
    atomicAdd(yp + 2, v * xv.z);
    atomicAdd(yp + 3, v * xv.w);
}

__global__ __launch_bounds__(THREADS) void spmm_g_items_kernel(
    const int* __restrict__ rows, const int* __restrict__ cols,
    const float* __restrict__ vals, const float* __restrict__ x,
    float* __restrict__ y_items, int nnz, int nU)
{
    long long gid = (long long)blockIdx.x * THREADS + threadIdx.x;
    int e = (int)(gid >> 4);
    if (e >= nnz) return;
    int r = rows[e];
    if (r < nU) return;
    int c = cols[e];
    if (c >= nU) return;
    int part = (int)(gid & 15);
    float v = vals[e];
    float4 xv = reinterpret_cast<const float4*>(x)[(long long)c * 16 + part];
    float* yp = y_items + (long long)(r - nU) * 64 + part * 4;
    atomicAdd(yp + 0, v * xv.x);
    atomicAdd(yp + 1, v * xv.y);
    atomicAdd(yp + 2, v * xv.z);
    atomicAdd(yp + 3, v * xv.w);
}

__global__ __launch_bounds__(THREADS) void combine_kernel(
    const float4* __restrict__ e0, float4* __restrict__ e1,
    const float4* __restrict__ e2, const float4* __restrict__ e3, int n4)
{
    int i = blockIdx.x * THREADS + threadIdx.x;
    if (i >= n4) return;
    float4 a = e0[i], b = e1[i], c = e2[i], d = e3[i];
    e1[i] = make_float4(0.25f * (a.x + b.x + c.x + d.x), 0.25f * (a.y + b.y + c.y + d.y),
                        0.25f * (a.z + b.z + c.z + d.z), 0.25f * (a.w + b.w + c.w + d.w));
}

// ---------------------------------------------------------------------------

extern "C" void kernel_launch(void* const* d_in, const int* in_sizes, int n_in,
                              void* d_out, int out_size, void* d_ws, size_t ws_size,
                              hipStream_t stream) {
    const float* user_emb = (const float*)d_in[0];
    const int*   uu_rows  = (const int*)d_in[1];
    const int*   uu_cols  = (const int*)d_in[2];
    const float* uu_vals  = (const float*)d_in[3];
    const int*   g_rows   = (const int*)d_in[4];
    const int*   g_cols   = (const int*)d_in[5];
    const float* g_vals   = (const float*)d_in[6];
    const int*   users    = (const int*)d_in[7];
    const int*   items    = (const int*)d_in[8];

    const int U    = in_sizes[0] / 64;     // 131072
    const int E_UU = in_sizes[1];          // 4000000
    const int E_G  = in_sizes[4];          // 4000000
    const int B    = in_sizes[7];          // 8192
    const int M    = 32768;                // num_items (fixed per reference)

    const size_t EMB = (size_t)U * 64 * sizeof(float);   // 32 MB
    const size_t MB  = 1024 * 1024;

    char* ws = (char*)d_ws;

    float* ACC = (float*)(ws);
    float* P0  = (float*)(ws + EMB);
    float* P1  = (float*)(ws + 2 * EMB);
    u64*   mid = (u64*)(ws);                               // aliases ACC during build
    int*  cnt_g = (int*)(ws + EMB);
    int*  rp_g  = (int*)(ws + EMB + 512 * 1024);
    int*  cur_g = (int*)(ws + EMB + 1 * MB);
    int2* se_g  = (int2*)(ws + EMB + MB + 512 * 1024);
    float* IT   = (float*)(ws + EMB + 34 * MB);
    char* base3 = ws + 3 * EMB;
    int*  bcnt    = (int*)(base3);
    int*  gcur    = (int*)(base3 + 4096);
    int*  bbase   = (int*)(base3 + 8192);
    int*  hbase   = (int*)(base3 + 12288);    // 513 ints
    int*  partial = (int*)(base3 + 1 * MB);
    u64*  se_u  = (u64*)(base3 + 2 * MB + 16 * 1024);
    const size_t needCSR = 3 * EMB + 2 * MB + 16 * 1024 + (size_t)E_UU * 8 + 1024;

    int n4 = U * 16;

    bool newPath = (ws_size >= needCSR) && (U == 131072) &&
                   ((size_t)E_UU * 8 <= EMB) && (E_UU > 0);

    if (newPath) {
        const int bshift = 9;
        // ---- build uu: row-bucket partition + (half, col-group) sort ----
        hipMemsetAsync(bcnt, 0, NB * 4, stream);
        bucket_hist<<<1024, THREADS, 0, stream>>>(uu_rows, E_UU, bshift, bcnt);
        scan_buckets<<<1, 64, 0, stream>>>(bcnt, bbase, gcur, hbase, E_UU);
        int nChunks = (E_UU + CHUNK - 1) / CHUNK;
        partition_uu<<<nChunks, THREADS, 0, stream>>>(uu_rows, uu_cols, uu_vals,
                                                      E_UU, bshift, mid, gcur);
        fine_colh<<<NB, THREADS, 0, stream>>>(mid, bbase, se_u, hbase);

        // ---- 3 tiled layers; ACC folding in epilogue ----
        spmm_tile2<<<NB * 2, THREADS, 0, stream>>>(se_u, hbase, user_emb, P0, ACC,
                                                   (const float*)nullptr, 1);
        spmm_tile2<<<NB * 2, THREADS, 0, stream>>>(se_u, hbase, P0, P1, ACC,
                                                   (const float*)nullptr, 2);
        spmm_tile2<<<NB * 2, THREADS, 0, stream>>>(se_u, hbase, P1, (float*)nullptr, ACC,
                                                   user_emb, 3);

        // ---- build g (item-row) CSR, filtered ----
        hipMemsetAsync(cnt_g, 0, (size_t)M * 4, stream);
        hist_g<<<4096, THREADS, 0, stream>>>(g_rows, g_cols, E_G, cnt_g, U);
        scan_block_sums<<<M / 512, THREADS, 0, stream>>>(cnt_g, partial);
        scan_partials<<<1, 64, 0, stream>>>(partial, M / 512, rp_g, M);
        scan_write<<<M / 512, THREADS, 0, stream>>>(cnt_g, partial, rp_g);
        hipMemcpyAsync(cur_g, rp_g, (size_t)M * 4, hipMemcpyDeviceToDevice, stream);
        scatter_g<<<4096, THREADS, 0, stream>>>(g_rows, g_cols, g_vals, E_G, cur_g, se_g, U);

        // ---- item propagation + gamma ----
        spmm_csr3<<<M / 4, THREADS, 0, stream>>>(rp_g, (const long long*)se_g, ACC, IT, M);
        final_dot_kernel<<<(B * 16 + THREADS - 1) / THREADS, THREADS, 0, stream>>>(
            ACC, IT, users, items, (float*)d_out, B);
    } else {
        // ---- fallback: atomic path ----
        float* E1 = (float*)ws;
        float* E2 = (float*)(ws + EMB);
        float* E3 = (float*)(ws + 2 * EMB);
        float* IT2 = (float*)(ws + 3 * EMB);
        const size_t itBytes = (size_t)M * 64 * sizeof(float);
        int spmmGrid = (int)(((long long)E_UU * 16 + THREADS - 1) / THREADS);
        int gGrid    = (int)(((long long)E_G * 16 + THREADS - 1) / THREADS);

        hipMemsetAsync(E1, 0, EMB, stream);
        spmm_atomic_kernel<<<spmmGrid, THREADS, 0, stream>>>(uu_rows, uu_cols, uu_vals, user_emb, E1, E_UU);
        hipMemsetAsync(E2, 0, EMB, stream);
        spmm_atomic_kernel<<<spmmGrid, THREADS, 0, stream>>>(uu_rows, uu_cols, uu_vals, E1, E2, E_UU);
        hipMemsetAsync(E3, 0, EMB, stream);
        spmm_atomic_kernel<<<spmmGrid, THREADS, 0, stream>>>(uu_rows, uu_cols, uu_vals, E2, E3, E_UU);
        combine_kernel<<<(n4 + THREADS - 1) / THREADS, THREADS, 0, stream>>>(
            (const float4*)user_emb, (float4*)E1, (const float4*)E2, (const float4*)E3, n4);
        hipMemsetAsync(IT2, 0, itBytes, stream);
        spmm_g_items_kernel<<<gGrid, THREADS, 0, stream>>>(g_rows, g_cols, g_vals, E1, IT2, E_G, U);
        final_dot_kernel<<<(B * 16 + THREADS - 1) / THREADS, THREADS, 0, stream>>>(
            E1, IT2, users, items, (float*)d_out, B);
    }
}

// Round 12
// 698.483 us; speedup vs baseline: 6.3321x; 6.0311x over previous
//
#include <hip/hip_runtime.h>
#include <hip/hip_bf16.h>

#define THREADS 256
#define NB 256        // row buckets for uu CSR build
#define CHUNK 2048    // edges per partition block
#define EPT 8         // CHUNK / THREADS

typedef unsigned long long u64;

// ---------------------------------------------------------------------------
// Fused histograms: uu row-bucket hist (LDS-aggregated) + filtered g item hist
// ---------------------------------------------------------------------------
__global__ __launch_bounds__(THREADS) void hist_fused(
    const int* __restrict__ uu_rows, int nuu, int bshift, int* __restrict__ bcnt,
    const int* __restrict__ g_rows, const int* __restrict__ g_cols, int ng,
    int* __restrict__ cnt_g, int nU)
{
    __shared__ int h[NB];
    h[threadIdx.x] = 0;
    __syncthreads();
    int stride = gridDim.x * THREADS;
    for (int e = blockIdx.x * THREADS + threadIdx.x; e < nuu; e += stride)
        atomicAdd(&h[uu_rows[e] >> bshift], 1);
    for (int e = blockIdx.x * THREADS + threadIdx.x; e < ng; e += stride) {
        int r = g_rows[e];
        if (r >= nU && g_cols[e] < nU) atomicAdd(&cnt_g[r - nU], 1);
    }
    __syncthreads();
    int v = h[threadIdx.x];
    if (v) atomicAdd(&bcnt[threadIdx.x], v);
}

// Single tiny kernel: bucket scan (uu) + partial scan (g) + sentinels.
__global__ void fused_scans(const int* __restrict__ bcnt, int* __restrict__ bbase,
                            int* __restrict__ gcur, int* __restrict__ rp_u, int U_, int E_,
                            int* __restrict__ partial, int nbp, int* __restrict__ rp_g, int M_)
{
    if (threadIdx.x == 0 && blockIdx.x == 0) {
        int run = 0;
        for (int i = 0; i < NB; i++) { bbase[i] = run; gcur[i] = run; run += bcnt[i]; }
        bbase[NB] = run;
        rp_u[U_] = E_;
        int rg = 0;
        for (int i = 0; i < nbp; i++) { int v = partial[i]; partial[i] = rg; rg += v; }
        rp_g[M_] = rg;
    }
}

// ---------------------------------------------------------------------------
// uu CSR build: LDS-staged partition into row buckets -> per-bucket row sort.
// mid payload: [63:32]=val bits, [28:20]=row&511, [19:0]=col
// ---------------------------------------------------------------------------
__global__ __launch_bounds__(THREADS) void partition_uu(
    const int* __restrict__ rows, const int* __restrict__ cols,
    const float* __restrict__ vals, int nnz, int bshift,
    u64* __restrict__ mid, int* __restrict__ gcur)
{
    __shared__ int hist[NB], lbase[NB], lcur[NB], gbase[NB];
    __shared__ u64 stage[CHUNK];
    __shared__ int dst[CHUNK];
    int t = threadIdx.x;
    long long cb = (long long)blockIdx.x * CHUNK;
    hist[t] = 0; lcur[t] = 0;
    __syncthreads();

    int rl[EPT], cl[EPT], vb[EPT];
    #pragma unroll
    for (int j = 0; j < EPT; j++) {
        long long e = cb + j * THREADS + t;
        if (e < nnz) {
            rl[j] = rows[e]; cl[j] = cols[e]; vb[j] = __float_as_int(vals[e]);
            atomicAdd(&hist[rl[j] >> bshift], 1);
        } else rl[j] = -1;
    }
    __syncthreads();

    int v = hist[t];
    lbase[t] = v;
    __syncthreads();
    for (int off = 1; off < NB; off <<= 1) {
        int add = (t >= off) ? lbase[t - off] : 0;
        __syncthreads();
        lbase[t] += add;
        __syncthreads();
    }
    int excl = lbase[t] - v;
    int gb = 0;
    if (v) gb = atomicAdd(&gcur[t], v);
    gbase[t] = gb;
    lbase[t] = excl;
    __syncthreads();

    #pragma unroll
    for (int j = 0; j < EPT; j++) {
        if (rl[j] >= 0) {
            int b = rl[j] >> bshift;
            int rank = atomicAdd(&lcur[b], 1);
            int pos = lbase[b] + rank;
            stage[pos] = ((u64)(unsigned)vb[j] << 32)
                       | ((unsigned)(rl[j] & ((1 << bshift) - 1)) << 20)
                       | (unsigned)cl[j];
            dst[pos] = gbase[b] + rank;
        }
    }
    __syncthreads();
    int total = lbase[NB - 1] + hist[NB - 1];
    for (int i = t; i < total; i += THREADS)
        mid[dst[i]] = stage[i];
}

// One block per bucket: per-row count -> scan -> rp write + L2-window scatter.
__global__ __launch_bounds__(THREADS) void fine_uu(
    const u64* __restrict__ mid, const int* __restrict__ bbase,
    int2* __restrict__ se, int* __restrict__ rp, int bshift)
{
    __shared__ int rcnt[512];
    __shared__ int sc[THREADS];
    int b = blockIdx.x, t = threadIdx.x;
    int s = bbase[b], e = bbase[b + 1];
    int rmask = (1 << bshift) - 1;
    rcnt[t] = 0; rcnt[t + 256] = 0;
    __syncthreads();
    for (int i = s + t; i < e; i += THREADS)
        atomicAdd(&rcnt[(int)(mid[i] >> 20) & rmask], 1);
    __syncthreads();
    int a0 = rcnt[2 * t], a1 = rcnt[2 * t + 1];
    int psum = a0 + a1;
    sc[t] = psum;
    __syncthreads();
    for (int off = 1; off < THREADS; off <<= 1) {
        int add = (t >= off) ? sc[t - off] : 0;
        __syncthreads();
        sc[t] += add;
        __syncthreads();
    }
    int pexcl = sc[t] - psum;
    int rowg = (b << bshift) + 2 * t;
    rp[rowg]     = s + pexcl;
    rp[rowg + 1] = s + pexcl + a0;
    rcnt[2 * t] = pexcl;
    rcnt[2 * t + 1] = pexcl + a0;
    __syncthreads();
    for (int i = s + t; i < e; i += THREADS) {
        u64 w = mid[i];
        int rloc = (int)(w >> 20) & rmask;
        int pos = s + atomicAdd(&rcnt[rloc], 1);
        se[pos] = make_int2((int)(w & 0xFFFFF), (int)(w >> 32));
    }
}

// ---------------------------------------------------------------------------
// g scans (item rows): block sums -> (fused serial) -> write; also fills cur_g
// ---------------------------------------------------------------------------
__global__ __launch_bounds__(THREADS) void scan_block_sums(
    const int* __restrict__ cnt, int* __restrict__ partial)
{
    __shared__ int lds[THREADS];
    int i = blockIdx.x * 512 + threadIdx.x * 2;
    lds[threadIdx.x] = cnt[i] + cnt[i + 1];
    __syncthreads();
    for (int off = 128; off > 0; off >>= 1) {
        if (threadIdx.x < off) lds[threadIdx.x] += lds[threadIdx.x + off];
        __syncthreads();
    }
    if (threadIdx.x == 0) partial[blockIdx.x] = lds[0];
}

__global__ __launch_bounds__(THREADS) void scan_write(
    const int* __restrict__ cnt, const int* __restrict__ partial,
    int* __restrict__ rp, int* __restrict__ cur)
{
    __shared__ int lds[THREADS];
    int t = threadIdx.x;
    int i = blockIdx.x * 512 + t * 2;
    int a0 = cnt[i], a1 = cnt[i + 1];
    int s = a0 + a1;
    lds[t] = s;
    __syncthreads();
    for (int off = 1; off < THREADS; off <<= 1) {
        int v = (t >= off) ? lds[t - off] : 0;
        __syncthreads();
        lds[t] += v;
        __syncthreads();
    }
    int excl = lds[t] - s;
    int base = partial[blockIdx.x];
    rp[i] = base + excl;         cur[i] = base + excl;
    rp[i + 1] = base + excl + a0; cur[i + 1] = base + excl + a0;
}

__global__ __launch_bounds__(THREADS) void scatter_g(
    const int* __restrict__ rows, const int* __restrict__ cols,
    const float* __restrict__ vals, int nnz, int* __restrict__ cur,
    int2* __restrict__ se, int nU)
{
    int stride = gridDim.x * THREADS;
    for (int e = blockIdx.x * THREADS + threadIdx.x; e < nnz; e += stride) {
        int r = rows[e];
        if (r >= nU) {
            int c = cols[e];
            if (c < nU) {
                int p = atomicAdd(&cur[r - nU], 1);
                se[p] = make_int2(c, __float_as_int(vals[e]));
            }
        }
    }
}

// ---------------------------------------------------------------------------
// Gather SpMM (round-7 proven): one wave per row, lane = feature.
// Cooperative edge fetch, readlane broadcast -> scalar-base gathers,
// 8 independent in-flight gathers.
// mode: 0 = y only, 1 = acc store, 2 = acc add, 3 = acc = 0.25*(ue+acc+a)
// ---------------------------------------------------------------------------
__global__ __launch_bounds__(THREADS) void spmm_csr2(
    const int* __restrict__ rp, const long long* __restrict__ se,
    const float* __restrict__ x, float* __restrict__ y,
    float* __restrict__ acc, const float* __restrict__ ue,
    int mode, int nrows)
{
    int w = (blockIdx.x * THREADS + threadIdx.x) >> 6;
    int lane = threadIdx.x & 63;
    if (w >= nrows) return;
    int s = rp[w], e = rp[w + 1];

    float a0 = 0.f, a1 = 0.f, a2 = 0.f, a3 = 0.f;
    float a4 = 0.f, a5 = 0.f, a6 = 0.f, a7 = 0.f;

    for (int base = s; base < e; base += 64) {
        int avail = e - base;
        long long packed = 0;
        if (lane < avail)
            packed = __builtin_nontemporal_load(se + base + lane);
        int evc = (int)(packed & 0xffffffffLL);
        int evv = (int)(packed >> 32);
        int n = avail < 64 ? avail : 64;
        int nIter = (n + 7) & ~7;
        for (int i = 0; i < nIter; i += 8) {
            int   c0 = __builtin_amdgcn_readlane(evc, i + 0);
            float v0 = __int_as_float(__builtin_amdgcn_readlane(evv, i + 0));
            int   c1 = __builtin_amdgcn_readlane(evc, i + 1);
            float v1 = __int_as_float(__builtin_amdgcn_readlane(evv, i + 1));
            int   c2 = __builtin_amdgcn_readlane(evc, i + 2);
            float v2 = __int_as_float(__builtin_amdgcn_readlane(evv, i + 2));
            int   c3 = __builtin_amdgcn_readlane(evc, i + 3);
            float v3 = __int_as_float(__builtin_amdgcn_readlane(evv, i + 3));
            int   c4 = __builtin_amdgcn_readlane(evc, i + 4);
            float v4 = __int_as_float(__builtin_amdgcn_readlane(evv, i + 4));
            int   c5 = __builtin_amdgcn_readlane(evc, i + 5);
            float v5 = __int_as_float(__builtin_amdgcn_readlane(evv, i + 5));
            int   c6 = __builtin_amdgcn_readlane(evc, i + 6);
            float v6 = __int_as_float(__builtin_amdgcn_readlane(evv, i + 6));
            int   c7 = __builtin_amdgcn_readlane(evc, i + 7);
            float v7 = __int_as_float(__builtin_amdgcn_readlane(evv, i + 7));
            float g0 = x[((long long)c0 << 6) + lane];
            float g1 = x[((long long)c1 << 6) + lane];
            float g2 = x[((long long)c2 << 6) + lane];
            float g3 = x[((long long)c3 << 6) + lane];
            float g4 = x[((long long)c4 << 6) + lane];
            float g5 = x[((long long)c5 << 6) + lane];
            float g6 = x[((long long)c6 << 6) + lane];
            float g7 = x[((long long)c7 << 6) + lane];
            a0 += v0 * g0; a1 += v1 * g1; a2 += v2 * g2; a3 += v3 * g3;
            a4 += v4 * g4; a5 += v5 * g5; a6 += v6 * g6; a7 += v7 * g7;
        }
    }
    float a = ((a0 + a1) + (a2 + a3)) + ((a4 + a5) + (a6 + a7));
    long long oi = ((long long)w << 6) + lane;
    if (y) __builtin_nontemporal_store(a, y + oi);
    if (mode == 1)      acc[oi] = a;
    else if (mode == 2) acc[oi] += a;
    else if (mode == 3) acc[oi] = 0.25f * (ue[oi] + acc[oi] + a);
}

__global__ __launch_bounds__(THREADS) void final_dot_kernel(
    const float* __restrict__ au, const float* __restrict__ it,
    const int* __restrict__ users, const int* __restrict__ items,
    float* __restrict__ out, int B)
{
    int gid = blockIdx.x * THREADS + threadIdx.x;
    int b = gid >> 4;
    if (b >= B) return;
    int part = gid & 15;
    float4 uv = reinterpret_cast<const float4*>(au)[(long long)users[b] * 16 + part];
    float4 iv = reinterpret_cast<const float4*>(it)[(long long)items[b] * 16 + part];
    float s = uv.x * iv.x + uv.y * iv.y + uv.z * iv.z + uv.w * iv.w;
    s += __shfl_xor(s, 1);
    s += __shfl_xor(s, 2);
    s += __shfl_xor(s, 4);
    s += __shfl_xor(s, 8);
    if (part == 0) out[b] = s;
}

// ---------------------------------------------------------------------------
// Fallback (atomic path)
// ---------------------------------------------------------------------------
__global__ __launch_bounds__(THREADS) void spmm_atomic_kernel(
    const int* __restrict__ rows, const int* __restrict__ cols,
    const float* __restrict__ vals, const float* __restrict__ x,
    float* __restrict__ y, int nnz)
{
    long long gid = (long long)blockIdx.x * THREADS + threadIdx.x;
    int e = (int)(gid >> 4);
    if (e >= nnz) return;
    int part = (int)(gid & 15);
    int r = rows[e];
    int c = cols[e];
    float v = vals[e];
    float4 xv = reinterpret_cast<const float4*>(x)[(long long)c * 16 + part];
    float* yp = y + (long long)r * 64 + part * 4;
    atomicAdd(yp + 0, v * xv.x);
    atomicAdd(yp + 1, v * xv.y);
    atomicAdd(yp + 2, v * xv.z);
    atomicAdd(yp + 3, v * xv.w);
}

__global__ __launch_bounds__(THREADS) void spmm_g_items_kernel(
    const int* __restrict__ rows, const int* __restrict__ cols,
    const float* __restrict__ vals, const float* __restrict__ x,
    float* __restrict__ y_items, int nnz, int nU)
{
    long long gid = (long long)blockIdx.x * THREADS + threadIdx.x;
    int e = (int)(gid >> 4);
    if (e >= nnz) return;
    int r = rows[e];
    if (r < nU) return;
    int c = cols[e];
    if (c >= nU) return;
    int part = (int)(gid & 15);
    float v = vals[e];
    float4 xv = reinterpret_cast<const float4*>(x)[(long long)c * 16 + part];
    float* yp = y_items + (long long)(r - nU) * 64 + part * 4;
    atomicAdd(yp + 0, v * xv.x);
    atomicAdd(yp + 1, v * xv.y);
    atomicAdd(yp + 2, v * xv.z);
    atomicAdd(yp + 3, v * xv.w);
}

__global__ __launch_bounds__(THREADS) void combine_kernel(
    const float4* __restrict__ e0, float4* __restrict__ e1,
    const float4* __restrict__ e2, const float4* __restrict__ e3, int n4)
{
    int i = blockIdx.x * THREADS + threadIdx.x;
    if (i >= n4) return;
    float4 a = e0[i], b = e1[i], c = e2[i], d = e3[i];
    e1[i] = make_float4(0.25f * (a.x + b.x + c.x + d.x), 0.25f * (a.y + b.y + c.y + d.y),
                        0.25f * (a.z + b.z + c.z + d.z), 0.25f * (a.w + b.w + c.w + d.w));
}

// ---------------------------------------------------------------------------

extern "C" void kernel_launch(void* const* d_in, const int* in_sizes, int n_in,
                              void* d_out, int out_size, void* d_ws, size_t ws_size,
                              hipStream_t stream) {
    const float* user_emb = (const float*)d_in[0];
    const int*   uu_rows  = (const int*)d_in[1];
    const int*   uu_cols  = (const int*)d_in[2];
    const float* uu_vals  = (const float*)d_in[3];
    const int*   g_rows   = (const int*)d_in[4];
    const int*   g_cols   = (const int*)d_in[5];
    const float* g_vals   = (const float*)d_in[6];
    const int*   users    = (const int*)d_in[7];
    const int*   items    = (const int*)d_in[8];

    const int U    = in_sizes[0] / 64;     // 131072
    const int E_UU = in_sizes[1];          // 4000000
    const int E_G  = in_sizes[4];          // 4000000
    const int B    = in_sizes[7];          // 8192
    const int M    = 32768;                // num_items (fixed per reference)

    const size_t EMB = (size_t)U * 64 * sizeof(float);   // 32 MB
    const size_t MB  = 1024 * 1024;
    const size_t KB  = 1024;

    char* ws = (char*)d_ws;

    float* ACC = (float*)(ws);
    float* P0  = (float*)(ws + EMB);
    float* P1  = (float*)(ws + 2 * EMB);
    u64*   mid = (u64*)(ws);                               // aliases ACC during build
    // g overlay (P0 region; only touched after P0 is dead)
    int2*  se_g = (int2*)(ws + EMB + MB);
    float* IT   = (float*)(ws + EMB + 34 * MB);
    // uu/control region
    char* base3 = ws + 3 * EMB;
    int*  bcnt    = (int*)(base3);                         // 1 KB
    int*  cnt_g   = (int*)(base3 + KB);                    // 128 KB (zeroed with bcnt)
    int*  gcur    = (int*)(base3 + 132 * KB);              // 1 KB
    int*  bbase   = (int*)(base3 + 136 * KB);              // NB+1 ints
    int*  partial = (int*)(base3 + 140 * KB);              // 64 ints
    int*  cur_g   = (int*)(base3 + 144 * KB);              // 128 KB
    int*  rp_g    = (int*)(base3 + 280 * KB);              // 128 KB + 4
    int*  rp_u    = (int*)(base3 + 1 * MB + 16 * KB);      // 512 KB + 4
    int2* se_u    = (int2*)(base3 + 2 * MB + 16 * KB);     // 32 MB
    const size_t needCSR = 3 * EMB + 2 * MB + 16 * KB + (size_t)E_UU * 8 + 1024;

    int n4 = U * 16;

    bool newPath = (ws_size >= needCSR) && (U == 131072) &&
                   ((size_t)E_UU * 8 <= EMB) && (E_UU > 0) && (M == 32768);

    if (newPath) {
        const int bshift = 9;
        // ---- histograms (fused), scans (fused) ----
        hipMemsetAsync(bcnt, 0, KB + 128 * KB, stream);   // bcnt + cnt_g
        hist_fused<<<4096, THREADS, 0, stream>>>(uu_rows, E_UU, bshift, bcnt,
                                                 g_rows, g_cols, E_G, cnt_g, U);
        scan_block_sums<<<M / 512, THREADS, 0, stream>>>(cnt_g, partial);
        fused_scans<<<1, 64, 0, stream>>>(bcnt, bbase, gcur, rp_u, U, E_UU,
                                          partial, M / 512, rp_g, M);
        scan_write<<<M / 512, THREADS, 0, stream>>>(cnt_g, partial, rp_g, cur_g);

        // ---- uu CSR build ----
        int nChunks = (E_UU + CHUNK - 1) / CHUNK;
        partition_uu<<<nChunks, THREADS, 0, stream>>>(uu_rows, uu_cols, uu_vals,
                                                      E_UU, bshift, mid, gcur);
        fine_uu<<<NB, THREADS, 0, stream>>>(mid, bbase, se_u, rp_u, bshift);

        // ---- 3 layers; ACC store/add/finalize folded ----
        spmm_csr2<<<U / 4, THREADS, 0, stream>>>(rp_u, (const long long*)se_u,
            user_emb, P0, ACC, (const float*)nullptr, 1, U);
        spmm_csr2<<<U / 4, THREADS, 0, stream>>>(rp_u, (const long long*)se_u,
            P0, P1, ACC, (const float*)nullptr, 2, U);
        spmm_csr2<<<U / 4, THREADS, 0, stream>>>(rp_u, (const long long*)se_u,
            P1, (float*)nullptr, ACC, user_emb, 3, U);

        // ---- g scatter (P0 region now dead) + item propagation + gamma ----
        scatter_g<<<4096, THREADS, 0, stream>>>(g_rows, g_cols, g_vals, E_G, cur_g, se_g, U);
        spmm_csr2<<<M / 4, THREADS, 0, stream>>>(rp_g, (const long long*)se_g,
            ACC, IT, (float*)nullptr, (const float*)nullptr, 0, M);
        final_dot_kernel<<<(B * 16 + THREADS - 1) / THREADS, THREADS, 0, stream>>>(
            ACC, IT, users, items, (float*)d_out, B);
    } else {
        // ---- fallback: atomic path ----
        float* E1 = (float*)ws;
        float* E2 = (float*)(ws + EMB);
        float* E3 = (float*)(ws + 2 * EMB);
        float* IT2 = (float*)(ws + 3 * EMB);
        const size_t itBytes = (size_t)M * 64 * sizeof(float);
        int spmmGrid = (int)(((long long)E_UU * 16 + THREADS - 1) / THREADS);
        int gGrid    = (int)(((long long)E_G * 16 + THREADS - 1) / THREADS);

        hipMemsetAsync(E1, 0, EMB, stream);
        spmm_atomic_kernel<<<spmmGrid, THREADS, 0, stream>>>(uu_rows, uu_cols, uu_vals, user_emb, E1, E_UU);
        hipMemsetAsync(E2, 0, EMB, stream);
        spmm_atomic_kernel<<<spmmGrid, THREADS, 0, stream>>>(uu_rows, uu_cols, uu_vals, E1, E2, E_UU);
        hipMemsetAsync(E3, 0, EMB, stream);
        spmm_atomic_kernel<<<spmmGrid, THREADS, 0, stream>>>(uu_rows, uu_cols, uu_vals, E2, E3, E_UU);
        combine_kernel<<<(n4 + THREADS - 1) / THREADS, THREADS, 0, stream>>>(
            (const float4*)user_emb, (float4*)E1, (const float4*)E2, (const float4*)E3, n4);
        hipMemsetAsync(IT2, 0, itBytes, stream);
        spmm_g_items_kernel<<<gGrid, THREADS, 0, stream>>>(g_rows, g_cols, g_vals, E1, IT2, E_G, U);
        final_dot_kernel<<<(B * 16 + THREADS - 1) / THREADS, THREADS, 0, stream>>>(
            E1, IT2, users, items, (float*)d_out, B);
    }
}

// Round 13
// 691.710 us; speedup vs baseline: 6.3941x; 1.0098x over previous
//
#include <hip/hip_runtime.h>
#include <hip/hip_bf16.h>

#define THREADS 256
#define NB 256        // row buckets for uu CSR build
#define CHUNK 2048    // edges per partition block
#define EPT 8         // CHUNK / THREADS

typedef unsigned long long u64;

// ---------------------------------------------------------------------------
// Fused histograms: uu row-bucket hist (LDS-aggregated) + filtered g item hist
// ---------------------------------------------------------------------------
__global__ __launch_bounds__(THREADS) void hist_fused(
    const int* __restrict__ uu_rows, int nuu, int bshift, int* __restrict__ bcnt,
    const int* __restrict__ g_rows, const int* __restrict__ g_cols, int ng,
    int* __restrict__ cnt_g, int nU)
{
    __shared__ int h[NB];
    h[threadIdx.x] = 0;
    __syncthreads();
    int stride = gridDim.x * THREADS;
    for (int e = blockIdx.x * THREADS + threadIdx.x; e < nuu; e += stride)
        atomicAdd(&h[uu_rows[e] >> bshift], 1);
    for (int e = blockIdx.x * THREADS + threadIdx.x; e < ng; e += stride) {
        int r = g_rows[e];
        if (r >= nU && g_cols[e] < nU) atomicAdd(&cnt_g[r - nU], 1);
    }
    __syncthreads();
    int v = h[threadIdx.x];
    if (v) atomicAdd(&bcnt[threadIdx.x], v);
}

// Single-block PARALLEL scans: bucket scan (256) + g partial scan (<=256)
// + sentinels. Replaces the 320-iteration single-thread serial kernel.
__global__ __launch_bounds__(THREADS) void scans_parallel(
    const int* __restrict__ bcnt, int* __restrict__ bbase, int* __restrict__ gcur,
    int* __restrict__ rp_u, int U_, int E_,
    int* __restrict__ partial, int nbp, int* __restrict__ rp_g, int M_)
{
    __shared__ int lds[THREADS];
    int t = threadIdx.x;
    // inclusive scan of bcnt
    int v = bcnt[t];
    lds[t] = v;
    __syncthreads();
    for (int off = 1; off < 256; off <<= 1) {
        int a = (t >= off) ? lds[t - off] : 0;
        __syncthreads();
        lds[t] += a;
        __syncthreads();
    }
    int excl = lds[t] - v;
    bbase[t] = excl;
    gcur[t]  = excl;
    if (t == 255) bbase[256] = lds[255];
    if (t == 0)   rp_u[U_] = E_;
    __syncthreads();
    // inclusive scan of g partials
    int p = (t < nbp) ? partial[t] : 0;
    lds[t] = p;
    __syncthreads();
    for (int off = 1; off < 256; off <<= 1) {
        int a = (t >= off) ? lds[t - off] : 0;
        __syncthreads();
        lds[t] += a;
        __syncthreads();
    }
    if (t < nbp) partial[t] = lds[t] - p;
    if (t == nbp - 1) rp_g[M_] = lds[t];
}

// ---------------------------------------------------------------------------
// uu CSR build: LDS-staged partition into row buckets -> per-bucket row sort.
// mid payload: [63:32]=val bits, [28:20]=row&511, [19:0]=col
// ---------------------------------------------------------------------------
__global__ __launch_bounds__(THREADS) void partition_uu(
    const int* __restrict__ rows, const int* __restrict__ cols,
    const float* __restrict__ vals, int nnz, int bshift,
    u64* __restrict__ mid, int* __restrict__ gcur)
{
    __shared__ int hist[NB], lbase[NB], lcur[NB], gbase[NB];
    __shared__ u64 stage[CHUNK];
    __shared__ int dst[CHUNK];
    int t = threadIdx.x;
    long long cb = (long long)blockIdx.x * CHUNK;
    hist[t] = 0; lcur[t] = 0;
    __syncthreads();

    int rl[EPT], cl[EPT], vb[EPT];
    #pragma unroll
    for (int j = 0; j < EPT; j++) {
        long long e = cb + j * THREADS + t;
        if (e < nnz) {
            rl[j] = rows[e]; cl[j] = cols[e]; vb[j] = __float_as_int(vals[e]);
            atomicAdd(&hist[rl[j] >> bshift], 1);
        } else rl[j] = -1;
    }
    __syncthreads();

    int v = hist[t];
    lbase[t] = v;
    __syncthreads();
    for (int off = 1; off < NB; off <<= 1) {
        int add = (t >= off) ? lbase[t - off] : 0;
        __syncthreads();
        lbase[t] += add;
        __syncthreads();
    }
    int excl = lbase[t] - v;
    int gb = 0;
    if (v) gb = atomicAdd(&gcur[t], v);
    gbase[t] = gb;
    lbase[t] = excl;
    __syncthreads();

    #pragma unroll
    for (int j = 0; j < EPT; j++) {
        if (rl[j] >= 0) {
            int b = rl[j] >> bshift;
            int rank = atomicAdd(&lcur[b], 1);
            int pos = lbase[b] + rank;
            stage[pos] = ((u64)(unsigned)vb[j] << 32)
                       | ((unsigned)(rl[j] & ((1 << bshift) - 1)) << 20)
                       | (unsigned)cl[j];
            dst[pos] = gbase[b] + rank;
        }
    }
    __syncthreads();
    int total = lbase[NB - 1] + hist[NB - 1];
    for (int i = t; i < total; i += THREADS)
        mid[dst[i]] = stage[i];
}

// One block per bucket: per-row count -> scan -> rp write + L2-window scatter.
__global__ __launch_bounds__(THREADS) void fine_uu(
    const u64* __restrict__ mid, const int* __restrict__ bbase,
    int2* __restrict__ se, int* __restrict__ rp, int bshift)
{
    __shared__ int rcnt[512];
    __shared__ int sc[THREADS];
    int b = blockIdx.x, t = threadIdx.x;
    int s = bbase[b], e = bbase[b + 1];
    int rmask = (1 << bshift) - 1;
    rcnt[t] = 0; rcnt[t + 256] = 0;
    __syncthreads();
    for (int i = s + t; i < e; i += THREADS)
        atomicAdd(&rcnt[(int)(mid[i] >> 20) & rmask], 1);
    __syncthreads();
    int a0 = rcnt[2 * t], a1 = rcnt[2 * t + 1];
    int psum = a0 + a1;
    sc[t] = psum;
    __syncthreads();
    for (int off = 1; off < THREADS; off <<= 1) {
        int add = (t >= off) ? sc[t - off] : 0;
        __syncthreads();
        sc[t] += add;
        __syncthreads();
    }
    int pexcl = sc[t] - psum;
    int rowg = (b << bshift) + 2 * t;
    rp[rowg]     = s + pexcl;
    rp[rowg + 1] = s + pexcl + a0;
    rcnt[2 * t] = pexcl;
    rcnt[2 * t + 1] = pexcl + a0;
    __syncthreads();
    for (int i = s + t; i < e; i += THREADS) {
        u64 w = mid[i];
        int rloc = (int)(w >> 20) & rmask;
        int pos = s + atomicAdd(&rcnt[rloc], 1);
        se[pos] = make_int2((int)(w & 0xFFFFF), (int)(w >> 32));
    }
}

// ---------------------------------------------------------------------------
// g scans (item rows): block sums -> (parallel single-block) -> write+cur
// ---------------------------------------------------------------------------
__global__ __launch_bounds__(THREADS) void scan_block_sums(
    const int* __restrict__ cnt, int* __restrict__ partial)
{
    __shared__ int lds[THREADS];
    int i = blockIdx.x * 512 + threadIdx.x * 2;
    lds[threadIdx.x] = cnt[i] + cnt[i + 1];
    __syncthreads();
    for (int off = 128; off > 0; off >>= 1) {
        if (threadIdx.x < off) lds[threadIdx.x] += lds[threadIdx.x + off];
        __syncthreads();
    }
    if (threadIdx.x == 0) partial[blockIdx.x] = lds[0];
}

__global__ __launch_bounds__(THREADS) void scan_write(
    const int* __restrict__ cnt, const int* __restrict__ partial,
    int* __restrict__ rp, int* __restrict__ cur)
{
    __shared__ int lds[THREADS];
    int t = threadIdx.x;
    int i = blockIdx.x * 512 + t * 2;
    int a0 = cnt[i], a1 = cnt[i + 1];
    int s = a0 + a1;
    lds[t] = s;
    __syncthreads();
    for (int off = 1; off < THREADS; off <<= 1) {
        int v = (t >= off) ? lds[t - off] : 0;
        __syncthreads();
        lds[t] += v;
        __syncthreads();
    }
    int excl = lds[t] - s;
    int base = partial[blockIdx.x];
    rp[i] = base + excl;         cur[i] = base + excl;
    rp[i + 1] = base + excl + a0; cur[i + 1] = base + excl + a0;
}

__global__ __launch_bounds__(THREADS) void scatter_g(
    const int* __restrict__ rows, const int* __restrict__ cols,
    const float* __restrict__ vals, int nnz, int* __restrict__ cur,
    int2* __restrict__ se, int nU)
{
    int stride = gridDim.x * THREADS;
    for (int e = blockIdx.x * THREADS + threadIdx.x; e < nnz; e += stride) {
        int r = rows[e];
        if (r >= nU) {
            int c = cols[e];
            if (c < nU) {
                int p = atomicAdd(&cur[r - nU], 1);
                se[p] = make_int2(c, __float_as_int(vals[e]));
            }
        }
    }
}

// ---------------------------------------------------------------------------
// Gather SpMM (proven): one wave per row, lane = feature.
// Cooperative edge fetch, readlane broadcast -> scalar-base gathers,
// 8 independent in-flight gathers.
// mode: 0 = y only, 1 = acc store, 2 = acc add, 3 = acc = 0.25*(ue+acc+a)
// ---------------------------------------------------------------------------
__global__ __launch_bounds__(THREADS) void spmm_csr2(
    const int* __restrict__ rp, const long long* __restrict__ se,
    const float* __restrict__ x, float* __restrict__ y,
    float* __restrict__ acc, const float* __restrict__ ue,
    int mode, int nrows)
{
    int w = (blockIdx.x * THREADS + threadIdx.x) >> 6;
    int lane = threadIdx.x & 63;
    if (w >= nrows) return;
    int s = rp[w], e = rp[w + 1];

    float a0 = 0.f, a1 = 0.f, a2 = 0.f, a3 = 0.f;
    float a4 = 0.f, a5 = 0.f, a6 = 0.f, a7 = 0.f;

    for (int base = s; base < e; base += 64) {
        int avail = e - base;
        long long packed = 0;
        if (lane < avail)
            packed = __builtin_nontemporal_load(se + base + lane);
        int evc = (int)(packed & 0xffffffffLL);
        int evv = (int)(packed >> 32);
        int n = avail < 64 ? avail : 64;
        int nIter = (n + 7) & ~7;
        for (int i = 0; i < nIter; i += 8) {
            int   c0 = __builtin_amdgcn_readlane(evc, i + 0);
            float v0 = __int_as_float(__builtin_amdgcn_readlane(evv, i + 0));
            int   c1 = __builtin_amdgcn_readlane(evc, i + 1);
            float v1 = __int_as_float(__builtin_amdgcn_readlane(evv, i + 1));
            int   c2 = __builtin_amdgcn_readlane(evc, i + 2);
            float v2 = __int_as_float(__builtin_amdgcn_readlane(evv, i + 2));
            int   c3 = __builtin_amdgcn_readlane(evc, i + 3);
            float v3 = __int_as_float(__builtin_amdgcn_readlane(evv, i + 3));
            int   c4 = __builtin_amdgcn_readlane(evc, i + 4);
            float v4 = __int_as_float(__builtin_amdgcn_readlane(evv, i + 4));
            int   c5 = __builtin_amdgcn_readlane(evc, i + 5);
            float v5 = __int_as_float(__builtin_amdgcn_readlane(evv, i + 5));
            int   c6 = __builtin_amdgcn_readlane(evc, i + 6);
            float v6 = __int_as_float(__builtin_amdgcn_readlane(evv, i + 6));
            int   c7 = __builtin_amdgcn_readlane(evc, i + 7);
            float v7 = __int_as_float(__builtin_amdgcn_readlane(evv, i + 7));
            float g0 = x[((long long)c0 << 6) + lane];
            float g1 = x[((long long)c1 << 6) + lane];
            float g2 = x[((long long)c2 << 6) + lane];
            float g3 = x[((long long)c3 << 6) + lane];
            float g4 = x[((long long)c4 << 6) + lane];
            float g5 = x[((long long)c5 << 6) + lane];
            float g6 = x[((long long)c6 << 6) + lane];
            float g7 = x[((long long)c7 << 6) + lane];
            a0 += v0 * g0; a1 += v1 * g1; a2 += v2 * g2; a3 += v3 * g3;
            a4 += v4 * g4; a5 += v5 * g5; a6 += v6 * g6; a7 += v7 * g7;
        }
    }
    float a = ((a0 + a1) + (a2 + a3)) + ((a4 + a5) + (a6 + a7));
    long long oi = ((long long)w << 6) + lane;
    if (y) __builtin_nontemporal_store(a, y + oi);
    if (mode == 1)      acc[oi] = a;
    else if (mode == 2) acc[oi] += a;
    else if (mode == 3) acc[oi] = 0.25f * (ue[oi] + acc[oi] + a);
}

__global__ __launch_bounds__(THREADS) void final_dot_kernel(
    const float* __restrict__ au, const float* __restrict__ it,
    const int* __restrict__ users, const int* __restrict__ items,
    float* __restrict__ out, int B)
{
    int gid = blockIdx.x * THREADS + threadIdx.x;
    int b = gid >> 4;
    if (b >= B) return;
    int part = gid & 15;
    float4 uv = reinterpret_cast<const float4*>(au)[(long long)users[b] * 16 + part];
    float4 iv = reinterpret_cast<const float4*>(it)[(long long)items[b] * 16 + part];
    float s = uv.x * iv.x + uv.y * iv.y + uv.z * iv.z + uv.w * iv.w;
    s += __shfl_xor(s, 1);
    s += __shfl_xor(s, 2);
    s += __shfl_xor(s, 4);
    s += __shfl_xor(s, 8);
    if (part == 0) out[b] = s;
}

// ---------------------------------------------------------------------------
// Fallback (atomic path)
// ---------------------------------------------------------------------------
__global__ __launch_bounds__(THREADS) void spmm_atomic_kernel(
    const int* __restrict__ rows, const int* __restrict__ cols,
    const float* __restrict__ vals, const float* __restrict__ x,
    float* __restrict__ y, int nnz)
{
    long long gid = (long long)blockIdx.x * THREADS + threadIdx.x;
    int e = (int)(gid >> 4);
    if (e >= nnz) return;
    int part = (int)(gid & 15);
    int r = rows[e];
    int c = cols[e];
    float v = vals[e];
    float4 xv = reinterpret_cast<const float4*>(x)[(long long)c * 16 + part];
    float* yp = y + (long long)r * 64 + part * 4;
    atomicAdd(yp + 0, v * xv.x);
    atomicAdd(yp + 1, v * xv.y);
    atomicAdd(yp + 2, v * xv.z);
    atomicAdd(yp + 3, v * xv.w);
}

__global__ __launch_bounds__(THREADS) void spmm_g_items_kernel(
    const int* __restrict__ rows, const int* __restrict__ cols,
    const float* __restrict__ vals, const float* __restrict__ x,
    float* __restrict__ y_items, int nnz, int nU)
{
    long long gid = (long long)blockIdx.x * THREADS + threadIdx.x;
    int e = (int)(gid >> 4);
    if (e >= nnz) return;
    int r = rows[e];
    if (r < nU) return;
    int c = cols[e];
    if (c >= nU) return;
    int part = (int)(gid & 15);
    float v = vals[e];
    float4 xv = reinterpret_cast<const float4*>(x)[(long long)c * 16 + part];
    float* yp = y_items + (long long)(r - nU) * 64 + part * 4;
    atomicAdd(yp + 0, v * xv.x);
    atomicAdd(yp + 1, v * xv.y);
    atomicAdd(yp + 2, v * xv.z);
    atomicAdd(yp + 3, v * xv.w);
}

__global__ __launch_bounds__(THREADS) void combine_kernel(
    const float4* __restrict__ e0, float4* __restrict__ e1,
    const float4* __restrict__ e2, const float4* __restrict__ e3, int n4)
{
    int i = blockIdx.x * THREADS + threadIdx.x;
    if (i >= n4) return;
    float4 a = e0[i], b = e1[i], c = e2[i], d = e3[i];
    e1[i] = make_float4(0.25f * (a.x + b.x + c.x + d.x), 0.25f * (a.y + b.y + c.y + d.y),
                        0.25f * (a.z + b.z + c.z + d.z), 0.25f * (a.w + b.w + c.w + d.w));
}

// ---------------------------------------------------------------------------

extern "C" void kernel_launch(void* const* d_in, const int* in_sizes, int n_in,
                              void* d_out, int out_size, void* d_ws, size_t ws_size,
                              hipStream_t stream) {
    const float* user_emb = (const float*)d_in[0];
    const int*   uu_rows  = (const int*)d_in[1];
    const int*   uu_cols  = (const int*)d_in[2];
    const float* uu_vals  = (const float*)d_in[3];
    const int*   g_rows   = (const int*)d_in[4];
    const int*   g_cols   = (const int*)d_in[5];
    const float* g_vals   = (const float*)d_in[6];
    const int*   users    = (const int*)d_in[7];
    const int*   items    = (const int*)d_in[8];

    const int U    = in_sizes[0] / 64;     // 131072
    const int E_UU = in_sizes[1];          // 4000000
    const int E_G  = in_sizes[4];          // 4000000
    const int B    = in_sizes[7];          // 8192
    const int M    = 32768;                // num_items (fixed per reference)

    const size_t EMB = (size_t)U * 64 * sizeof(float);   // 32 MB
    const size_t MB  = 1024 * 1024;
    const size_t KB  = 1024;

    char* ws = (char*)d_ws;

    float* ACC = (float*)(ws);
    float* P0  = (float*)(ws + EMB);
    float* P1  = (float*)(ws + 2 * EMB);
    u64*   mid = (u64*)(ws);                               // aliases ACC during build
    // g overlay (P0 region; only touched after P0 is dead)
    int2*  se_g = (int2*)(ws + EMB + MB);
    float* IT   = (float*)(ws + EMB + 34 * MB);
    // uu/control region
    char* base3 = ws + 3 * EMB;
    int*  bcnt    = (int*)(base3);                         // 1 KB
    int*  cnt_g   = (int*)(base3 + KB);                    // 128 KB (zeroed with bcnt)
    int*  gcur    = (int*)(base3 + 132 * KB);              // 1 KB
    int*  bbase   = (int*)(base3 + 136 * KB);              // NB+1 ints
    int*  partial = (int*)(base3 + 140 * KB);              // 64 ints
    int*  cur_g   = (int*)(base3 + 144 * KB);              // 128 KB
    int*  rp_g    = (int*)(base3 + 280 * KB);              // 128 KB + 4
    int*  rp_u    = (int*)(base3 + 1 * MB + 16 * KB);      // 512 KB + 4
    int2* se_u    = (int2*)(base3 + 2 * MB + 16 * KB);     // 32 MB
    const size_t needCSR = 3 * EMB + 2 * MB + 16 * KB + (size_t)E_UU * 8 + 1024;

    int n4 = U * 16;

    bool newPath = (ws_size >= needCSR) && (U == 131072) &&
                   ((size_t)E_UU * 8 <= EMB) && (E_UU > 0) && (M == 32768);

    if (newPath) {
        const int bshift = 9;
        // ---- histograms (fused), scans (parallel) ----
        hipMemsetAsync(bcnt, 0, KB + 128 * KB, stream);   // bcnt + cnt_g
        hist_fused<<<4096, THREADS, 0, stream>>>(uu_rows, E_UU, bshift, bcnt,
                                                 g_rows, g_cols, E_G, cnt_g, U);
        scan_block_sums<<<M / 512, THREADS, 0, stream>>>(cnt_g, partial);
        scans_parallel<<<1, THREADS, 0, stream>>>(bcnt, bbase, gcur, rp_u, U, E_UU,
                                                  partial, M / 512, rp_g, M);
        scan_write<<<M / 512, THREADS, 0, stream>>>(cnt_g, partial, rp_g, cur_g);

        // ---- uu CSR build ----
        int nChunks = (E_UU + CHUNK - 1) / CHUNK;
        partition_uu<<<nChunks, THREADS, 0, stream>>>(uu_rows, uu_cols, uu_vals,
                                                      E_UU, bshift, mid, gcur);
        fine_uu<<<NB, THREADS, 0, stream>>>(mid, bbase, se_u, rp_u, bshift);

        // ---- 3 layers; ACC store/add/finalize folded ----
        spmm_csr2<<<U / 4, THREADS, 0, stream>>>(rp_u, (const long long*)se_u,
            user_emb, P0, ACC, (const float*)nullptr, 1, U);
        spmm_csr2<<<U / 4, THREADS, 0, stream>>>(rp_u, (const long long*)se_u,
            P0, P1, ACC, (const float*)nullptr, 2, U);
        spmm_csr2<<<U / 4, THREADS, 0, stream>>>(rp_u, (const long long*)se_u,
            P1, (float*)nullptr, ACC, user_emb, 3, U);

        // ---- g scatter (P0 region now dead) + item propagation + gamma ----
        scatter_g<<<4096, THREADS, 0, stream>>>(g_rows, g_cols, g_vals, E_G, cur_g, se_g, U);
        spmm_csr2<<<M / 4, THREADS, 0, stream>>>(rp_g, (const long long*)se_g,
            ACC, IT, (float*)nullptr, (const float*)nullptr, 0, M);
        final_dot_kernel<<<(B * 16 + THREADS - 1) / THREADS, THREADS, 0, stream>>>(
            ACC, IT, users, items, (float*)d_out, B);
    } else {
        // ---- fallback: atomic path ----
        float* E1 = (float*)ws;
        float* E2 = (float*)(ws + EMB);
        float* E3 = (float*)(ws + 2 * EMB);
        float* IT2 = (float*)(ws + 3 * EMB);
        const size_t itBytes = (size_t)M * 64 * sizeof(float);
        int spmmGrid = (int)(((long long)E_UU * 16 + THREADS - 1) / THREADS);
        int gGrid    = (int)(((long long)E_G * 16 + THREADS - 1) / THREADS);

        hipMemsetAsync(E1, 0, EMB, stream);
        spmm_atomic_kernel<<<spmmGrid, THREADS, 0, stream>>>(uu_rows, uu_cols, uu_vals, user_emb, E1, E_UU);
        hipMemsetAsync(E2, 0, EMB, stream);
        spmm_atomic_kernel<<<spmmGrid, THREADS, 0, stream>>>(uu_rows, uu_cols, uu_vals, E1, E2, E_UU);
        hipMemsetAsync(E3, 0, EMB, stream);
        spmm_atomic_kernel<<<spmmGrid, THREADS, 0, stream>>>(uu_rows, uu_cols, uu_vals, E2, E3, E_UU);
        combine_kernel<<<(n4 + THREADS - 1) / THREADS, THREADS, 0, stream>>>(
            (const float4*)user_emb, (float4*)E1, (const float4*)E2, (const float4*)E3, n4);
        hipMemsetAsync(IT2, 0, itBytes, stream);
        spmm_g_items_kernel<<<gGrid, THREADS, 0, stream>>>(g_rows, g_cols, g_vals, E1, IT2, E_G, U);
        final_dot_kernel<<<(B * 16 + THREADS - 1) / THREADS, THREADS, 0, stream>>>(
            E1, IT2, users, items, (float*)d_out, B);
    }
}